// Round 4
// baseline (447.020 us; speedup 1.0000x reference)
//
#include <hip/hip_runtime.h>
#include <hip/hip_bf16.h>

using bf16 = __hip_bfloat16;
typedef __attribute__((ext_vector_type(8))) short bf16x8;
typedef __attribute__((ext_vector_type(4))) float f32x4;

#define DEV __device__ __forceinline__

#define AS1 __attribute__((address_space(1)))
#define AS3 __attribute__((address_space(3)))
#define SB  __builtin_amdgcn_sched_barrier(0)
#define BARR __builtin_amdgcn_s_barrier()
#define LG0 asm volatile("s_waitcnt lgkmcnt(0)" ::: "memory")
#define VM4 asm volatile("s_waitcnt vmcnt(4)" ::: "memory")
#define VM0 asm volatile("s_waitcnt vmcnt(0)" ::: "memory")

// ---------------------------------------------------------------------------
// constants
static constexpr int Bsz = 8, Nseq = 512, Dm = 768, Vv = 30000, Yv = 30000;
static constexpr int Ypad = 30208;               // 118 tiles of 256
static constexpr int NTILE = 118;
static constexpr int Tok = Bsz * Nseq;           // 4096
static constexpr int NT = Dm / 64;               // 12 K-tiles of 64

// 16-MFMA cluster for quadrant (MQ,NQ) with B regs BR, setprio-wrapped (T5)
#define MF16(MQ, NQ, BR)                                                      \
    __builtin_amdgcn_s_setprio(1);                                            \
    _Pragma("unroll") for (int mm = 0; mm < 4; ++mm)                          \
    _Pragma("unroll") for (int nn = 0; nn < 2; ++nn) {                        \
        acc[(MQ)*4+mm][(NQ)*2+nn] = __builtin_amdgcn_mfma_f32_16x16x32_bf16(  \
            afr[mm][0], BR[nn][0], acc[(MQ)*4+mm][(NQ)*2+nn], 0, 0, 0);       \
        acc[(MQ)*4+mm][(NQ)*2+nn] = __builtin_amdgcn_mfma_f32_16x16x32_bf16(  \
            afr[mm][1], BR[nn][1], acc[(MQ)*4+mm][(NQ)*2+nn], 0, 0, 0);       \
    }                                                                         \
    __builtin_amdgcn_s_setprio(0);

// ---------------------------------------------------------------------------
// Big GEMM: C[4096][Yv] f32 = A[4096][768]_bf16 * B[Ypad][768]_bf16^T
// Persistent: 256 blocks (1/CU); block b: mTile=b>>4, stream s=b&15,
// nTile = s, s+16, ...  (b%8 == s%8 -> stream pinned to one XCD L2).
// Per tile: 256x256, BK=64, 8 waves, 8-phase schedule, 128 KiB LDS.
// Chunks: ci = slot*4 + op*2 + h  (op: A=0,B=1; h: 128-row half; slot: parity)
__global__ __launch_bounds__(512, 2)
void gemm_big(const bf16* __restrict__ Ag, const bf16* __restrict__ Bg,
              float* __restrict__ Cg)
{
    __shared__ bf16 sm[8][8192];                 // 8 x 16 KiB = 128 KiB

    const int b = blockIdx.x;
    const int mTile = b >> 4;                    // 0..15
    const int sIdx  = b & 15;                    // stream 0..15

    const int tid  = threadIdx.x;
    const int lane = tid & 63;
    const int wid  = tid >> 6;
    const int wm   = wid >> 2;                   // 0..1
    const int wn   = wid & 3;                    // 0..3

    // staging: thread covers LDS 16B-chunk (l*512+tid); row=c/8, slot8=c&7.
    // swizzle: LDS slot s of row r holds source col-chunk s^(r&7)
    const int lr = tid >> 3;
    const int sc = ((tid & 7) ^ (lr & 7)) << 3;
    const bf16* aS = Ag + (long)(mTile * 256 + lr) * Dm + sc;
    const int ldsOff = wid << 9;

    // frag read geometry
    const int fl = lane & 15;
    const int fh = lane >> 4;
    const int e0 = (fh ^ (fl & 7)) << 3;
    const int aro = (wm * 64 + fl) * 64;
    const int bro = (wn * 32 + fl) * 64;

    bf16x8 afr[4][2], b0r[2][2], b1r[2][2];

#define STAGE(CI, OP, H, TILE)                                                 \
    {                                                                          \
        const bf16* _s = ((OP) ? bS : aS) + (long)(H) * 128 * Dm + (TILE) * 64;\
        __builtin_amdgcn_global_load_lds((const AS1 void*)_s,                  \
            (AS3 void*)&sm[CI][ldsOff], 16, 0, 0);                             \
        __builtin_amdgcn_global_load_lds((const AS1 void*)(_s + (long)64 * Dm),\
            (AS3 void*)&sm[CI][4096 + ldsOff], 16, 0, 0);                      \
    }
#define RDA(CI)                                                                \
    _Pragma("unroll") for (int mm = 0; mm < 4; ++mm) {                         \
        afr[mm][0] = *(const bf16x8*)&sm[CI][aro + mm * 1024 + e0];            \
        afr[mm][1] = *(const bf16x8*)&sm[CI][aro + mm * 1024 + (e0 ^ 32)];     \
    }
#define RDB(BR, CI)                                                            \
    _Pragma("unroll") for (int nn = 0; nn < 2; ++nn) {                         \
        BR[nn][0] = *(const bf16x8*)&sm[CI][bro + nn * 1024 + e0];             \
        BR[nn][1] = *(const bf16x8*)&sm[CI][bro + nn * 1024 + (e0 ^ 32)];      \
    }

#pragma unroll 1
    for (int nTile = sIdx; nTile < NTILE; nTile += 16) {
        const bf16* bS = Bg + (long)(nTile * 256 + lr) * Dm + sc;
        f32x4 acc[8][4] = {};

        // prologue: tile0 {A0,B0,B1,A1} + tile1 {A0,B1}
        STAGE(0, 0, 0, 0) STAGE(2, 1, 0, 0) STAGE(3, 1, 1, 0) STAGE(1, 0, 1, 0)
        STAGE(4, 0, 0, 1) STAGE(7, 1, 1, 1)
        VM4; SB; BARR; SB;

#pragma unroll 1
        for (int t = 0; t < NT - 2; t += 2) {
            // p0: quad(0,0) tile t (slot0)
            STAGE(6, 1, 0, t + 1)                // B0 s1
            RDA(0) RDB(b0r, 2)
            SB; BARR; LG0; SB;
            MF16(0, 0, b0r)
            SB; BARR; SB;
            // p1: quad(0,1)
            STAGE(5, 0, 1, t + 1)                // A1 s1
            RDB(b1r, 3)
            SB; BARR; LG0; SB;
            MF16(0, 1, b1r)
            SB; BARR; SB;
            // p2: quad(1,1)
            STAGE(0, 0, 0, t + 2)                // A0 s0
            RDA(1)
            SB; BARR; LG0; SB;
            MF16(1, 1, b1r)
            SB; BARR; SB;
            // p3: quad(1,0) -- LDS-free phase
            STAGE(3, 1, 1, t + 2)                // B1 s0
            VM4; SB; BARR; SB;
            MF16(1, 0, b0r)
            SB; BARR; SB;
            // p4: quad(0,0) tile t+1 (slot1)
            STAGE(2, 1, 0, t + 2)                // B0 s0
            RDA(4) RDB(b0r, 6)
            SB; BARR; LG0; SB;
            MF16(0, 0, b0r)
            SB; BARR; SB;
            // p5: quad(0,1)
            STAGE(1, 0, 1, t + 2)                // A1 s0
            RDB(b1r, 7)
            SB; BARR; LG0; SB;
            MF16(0, 1, b1r)
            SB; BARR; SB;
            // p6: quad(1,1)
            STAGE(4, 0, 0, t + 3)                // A0 s1
            RDA(5)
            SB; BARR; LG0; SB;
            MF16(1, 1, b1r)
            SB; BARR; SB;
            // p7: quad(1,0) -- LDS-free phase
            STAGE(7, 1, 1, t + 3)                // B1 s1
            VM4; SB; BARR; SB;
            MF16(1, 0, b0r)
            SB; BARR; SB;
        }

        // peeled final iter (tiles NT-2, NT-1)
        {
            const int t = NT - 2;
            STAGE(6, 1, 0, t + 1)
            RDA(0) RDB(b0r, 2)
            SB; BARR; LG0; SB;
            MF16(0, 0, b0r)
            SB; BARR; SB;
            STAGE(5, 0, 1, t + 1)
            RDB(b1r, 3)
            SB; BARR; LG0; SB;
            MF16(0, 1, b1r)
            SB; BARR; SB;
            RDA(1)
            SB; BARR; LG0; SB;
            MF16(1, 1, b1r)
            SB; BARR; SB;
            VM0; SB; BARR; SB;
            MF16(1, 0, b0r)
            SB; BARR; SB;
            RDA(4) RDB(b0r, 6)
            SB; BARR; LG0; SB;
            MF16(0, 0, b0r)
            SB; BARR; SB;
            RDB(b1r, 7)
            SB; BARR; LG0; SB;
            MF16(0, 1, b1r)
            SB; BARR; SB;
            RDA(5)
            SB; BARR; LG0; SB;
            MF16(1, 1, b1r)
            SB; BARR; SB;
            SB; BARR; SB;                        // publish all LDS reads
            MF16(1, 0, b0r)
        }

        // epilogue: rows {wm*64}∪{128+wm*64}, cols {wn*32}∪{128+wn*32}
        const int rB = mTile * 256 + wm * 64 + fh * 4;
        const int cB = nTile * 256 + wn * 32 + fl;
#pragma unroll
        for (int mq = 0; mq < 2; ++mq)
#pragma unroll
        for (int mm = 0; mm < 4; ++mm)
#pragma unroll
        for (int nq = 0; nq < 2; ++nq)
#pragma unroll
        for (int nn = 0; nn < 2; ++nn) {
            const int c = cB + nq * 128 + nn * 16;
            if (c >= Yv) continue;
            const int r = rB + mq * 128 + mm * 16;
#pragma unroll
            for (int j = 0; j < 4; ++j)
                Cg[(long)(r + j) * Yv + c] = acc[mq * 4 + mm][nq * 2 + nn][j];
        }
    }
#undef STAGE
#undef RDA
#undef RDB
}

// ---------------------------------------------------------------------------
// GEMM: C[M][Nc] = A[M][K](lda) * B[Nc][K]^T   (m97-structure, small GEMMs)
template<bool STORE_BF16>
__global__ __launch_bounds__(256)
void gemm_bt(const bf16* __restrict__ Ag, const bf16* __restrict__ Bg,
             void* __restrict__ Cg, int M, int Nc, int K, int lda, int ldc,
             long sA, long sB, long sC)
{
    __shared__ bf16 As[128 * 32];
    __shared__ bf16 Bs[128 * 32];

    const int bz = blockIdx.z;
    const bf16* A  = Ag + (long)bz * sA;
    const bf16* Bm = Bg + (long)bz * sB;

    const int bid = blockIdx.x;
    const int nTilesM = M >> 7;
    const int mTile = bid % nTilesM;
    const int nTile = bid / nTilesM;

    const int tid  = threadIdx.x;
    const int wave = tid >> 6;
    const int lane = tid & 63;

    const int sRow = (wave << 4) + (lane >> 2);
    const int sCol = (lane & 3) << 3;

    const long aBase = (long)(mTile * 128) * lda;
    const long bBase = (long)(nTile * 128) * K;

    const int fl = lane & 15;
    const int fh = lane >> 4;
    const int wRow = (wave >> 1) << 6;
    const int wCol = (wave & 1) << 6;

    f32x4 acc[4][4] = {};

    for (int k0 = 0; k0 < K; k0 += 32) {
#pragma unroll
        for (int t = 0; t < 2; ++t) {
            const bf16* gA = A  + aBase + (long)(t * 64 + sRow) * lda + (k0 + sCol);
            const bf16* gB = Bm + bBase + (long)(t * 64 + sRow) * K + (k0 + sCol);
            bf16* lA = &As[(t * 64 + (wave << 4)) * 32];
            bf16* lB = &Bs[(t * 64 + (wave << 4)) * 32];
            __builtin_amdgcn_global_load_lds(
                (const AS1 void*)gA, (AS3 void*)lA, 16, 0, 0);
            __builtin_amdgcn_global_load_lds(
                (const AS1 void*)gB, (AS3 void*)lB, 16, 0, 0);
        }
        __syncthreads();

        bf16x8 af[4], bfg[4];
#pragma unroll
        for (int m = 0; m < 4; ++m)
            af[m] = *(const bf16x8*)&As[(wRow + m * 16 + fl) * 32 + fh * 8];
#pragma unroll
        for (int n = 0; n < 4; ++n)
            bfg[n] = *(const bf16x8*)&Bs[(wCol + n * 16 + fl) * 32 + fh * 8];
#pragma unroll
        for (int m = 0; m < 4; ++m)
#pragma unroll
            for (int n = 0; n < 4; ++n)
                acc[m][n] = __builtin_amdgcn_mfma_f32_16x16x32_bf16(
                    af[m], bfg[n], acc[m][n], 0, 0, 0);
        __syncthreads();
    }

    const int rBase = mTile * 128 + wRow + fh * 4;
    const int cBase = nTile * 128 + wCol + fl;
#pragma unroll
    for (int m = 0; m < 4; ++m) {
#pragma unroll
        for (int n = 0; n < 4; ++n) {
            int gc = cBase + n * 16;
            int gr = rBase + m * 16;
            if (STORE_BF16) {
                bf16* C = (bf16*)Cg + (long)bz * sC;
#pragma unroll
                for (int j = 0; j < 4; ++j)
                    C[(long)(gr + j) * ldc + gc] = __float2bfloat16(acc[m][n][j]);
            } else {
                float* C = (float*)Cg + (long)bz * sC;
#pragma unroll
                for (int j = 0; j < 4; ++j)
                    C[(long)(gr + j) * ldc + gc] = acc[m][n][j];
            }
        }
    }
}

// ---------------------------------------------------------------------------
// E_y f32 [30000][768] -> bf16 [30208][768], rows >= 30000 zero-filled
__global__ __launch_bounds__(192) void k_cvt_ey(const float* __restrict__ Ey,
                                                bf16* __restrict__ Eyb)
{
    int row = blockIdx.x;
    int d = threadIdx.x * 4;
    union { bf16 h[4]; uint2 u; } pk;
    if (row < Yv) {
        float4 v = *(const float4*)(Ey + (long)row * Dm + d);
        pk.h[0] = __float2bfloat16(v.x); pk.h[1] = __float2bfloat16(v.y);
        pk.h[2] = __float2bfloat16(v.z); pk.h[3] = __float2bfloat16(v.w);
    } else {
        pk.h[0] = pk.h[1] = pk.h[2] = pk.h[3] = __float2bfloat16(0.f);
    }
    *(uint2*)(Eyb + (long)row * Dm + d) = pk.u;
}

// W f32 [768][768] -> Wcat^T bf16 [1536][768]; z=0: W_A rows 0-767, z=1: W_O
__global__ void k_wT(const float* __restrict__ WA, const float* __restrict__ WO,
                     bf16* __restrict__ Wcat)
{
    __shared__ float t[32][33];
    const float* W = blockIdx.z ? WO : WA;
    bf16* WT = Wcat + (size_t)blockIdx.z * Dm * Dm;
    int bx = blockIdx.x * 32;
    int by = blockIdx.y * 32;
    int tx = threadIdx.x, ty = threadIdx.y;
#pragma unroll
    for (int i = 0; i < 32; i += 8)
        t[ty + i][tx] = W[(long)(bx + ty + i) * Dm + (by + tx)];
    __syncthreads();
#pragma unroll
    for (int i = 0; i < 32; i += 8)
        WT[(long)(by + ty + i) * Dm + (bx + tx)] = __float2bfloat16(t[tx][ty + i]);
}

// X = E_v[M_s] -> bf16 [4096][768]
__global__ __launch_bounds__(192) void k_gather(const int* __restrict__ Ms,
                                                const float* __restrict__ Ev,
                                                bf16* __restrict__ Xb)
{
    int token = blockIdx.x;
    int id = Ms[token];
    int d = threadIdx.x * 4;
    float4 v = *(const float4*)(Ev + (long)id * Dm + d);
    union { bf16 h[4]; uint2 u; } pk;
    pk.h[0] = __float2bfloat16(v.x); pk.h[1] = __float2bfloat16(v.y);
    pk.h[2] = __float2bfloat16(v.z); pk.h[3] = __float2bfloat16(v.w);
    *(uint2*)(Xb + (long)token * Dm + d) = pk.u;
}

// XWo slice of QXW bf16 [B][512][1536](+768) -> [B][768][512]
__global__ void k_xwoT(const bf16* __restrict__ Xo, bf16* __restrict__ XoT)
{
    __shared__ bf16 t[32][33];
    int b = blockIdx.z;
    const bf16* src = Xo + (long)b * Nseq * 1536 + 768;
    bf16* dst = XoT + (long)b * Dm * Nseq;
    int bx = blockIdx.x * 32;
    int by = blockIdx.y * 32;
    int tx = threadIdx.x, ty = threadIdx.y;
#pragma unroll
    for (int i = 0; i < 32; i += 8)
        t[ty + i][tx] = src[(long)(bx + ty + i) * 1536 + (by + tx)];
    __syncthreads();
#pragma unroll
    for (int i = 0; i < 32; i += 8)
        dst[(long)(by + ty + i) * Nseq + (bx + tx)] = t[tx][ty + i];
}

// ---------------------------------------------------------------------------
DEV float waveMax(float v) {
#pragma unroll
    for (int o = 32; o > 0; o >>= 1) v = fmaxf(v, __shfl_xor(v, o, 64));
    return v;
}
DEV float waveSum(float v) {
#pragma unroll
    for (int o = 32; o > 0; o >>= 1) v += __shfl_xor(v, o, 64);
    return v;
}

// softmax over j of (L[b,i,j] + (j-i)) with mask; writes A f32 (d_out) + bf16
__global__ __launch_bounds__(256) void k_softmax(const float* __restrict__ L,
                                                 const int* __restrict__ Ms,
                                                 float* __restrict__ Aout,
                                                 bf16* __restrict__ Ab)
{
    __shared__ float red[8];
    int row = blockIdx.x;
    int b = row >> 9, i = row & 511;
    const float* l = L + (long)row * Nseq;
    const int* ms = Ms + (b << 9);
    int t = threadIdx.x;
    int wid = t >> 6, lane = t & 63;
    int j0 = t, j1 = t + 256;

    float a0 = l[j0] + (float)(j0 - i);
    float a1 = l[j1] + (float)(j1 - i);
    if (ms[j0] == 0) a0 = -1e12f;
    if (ms[j1] == 0) a1 = -1e12f;

    float m = waveMax(fmaxf(a0, a1));
    if (lane == 0) red[wid] = m;
    __syncthreads();
    m = fmaxf(fmaxf(red[0], red[1]), fmaxf(red[2], red[3]));

    float e0 = expf(a0 - m), e1 = expf(a1 - m);
    float s = waveSum(e0 + e1);
    if (lane == 0) red[4 + wid] = s;
    __syncthreads();
    s = red[4] + red[5] + red[6] + red[7];
    float inv = 1.0f / s;

    float r0 = e0 * inv, r1 = e1 * inv;
    Aout[(long)row * Nseq + j0] = r0;
    Aout[(long)row * Nseq + j1] = r1;
    Ab[(long)row * Nseq + j0] = __float2bfloat16(r0);
    Ab[(long)row * Nseq + j1] = __float2bfloat16(r1);
}

// H = LN(Qc + E_v[Ms]) * gamma + beta  -> bf16
__global__ __launch_bounds__(256) void k_ln(const float* __restrict__ Qc,
                                            const int* __restrict__ Ms,
                                            const float* __restrict__ Ev,
                                            const float* __restrict__ gamma,
                                            const float* __restrict__ beta,
                                            bf16* __restrict__ Hb)
{
    __shared__ float red[8];
    int row = blockIdx.x;
    int id = Ms[row];
    const float* q = Qc + (long)row * Dm;
    const float* e = Ev + (long)id * Dm;
    int t = threadIdx.x;
    int wid = t >> 6, lane = t & 63;

    float x[3];
#pragma unroll
    for (int c = 0; c < 3; ++c) x[c] = q[t + c * 256] + e[t + c * 256];

    float s = waveSum(x[0] + x[1] + x[2]);
    if (lane == 0) red[wid] = s;
    __syncthreads();
    float mu = (red[0] + red[1] + red[2] + red[3]) * (1.0f / 768.0f);

    float vs = 0.f;
#pragma unroll
    for (int c = 0; c < 3; ++c) { float d = x[c] - mu; vs += d * d; }
    vs = waveSum(vs);
    if (lane == 0) red[4 + wid] = vs;
    __syncthreads();
    float var = (red[4] + red[5] + red[6] + red[7]) * (1.0f / 768.0f);
    float rstd = rsqrtf(var + 1e-5f);

#pragma unroll
    for (int c = 0; c < 3; ++c) {
        int d = t + c * 256;
        Hb[(long)row * Dm + d] =
            __float2bfloat16((x[c] - mu) * rstd * gamma[d] + beta[d]);
    }
}

// ---------------------------------------------------------------------------
extern "C" void kernel_launch(void* const* d_in, const int* in_sizes, int n_in,
                              void* d_out, int out_size, void* d_ws, size_t ws_size,
                              hipStream_t stream)
{
    const int*   Ms    = (const int*)d_in[0];
    const float* Ev    = (const float*)d_in[1];
    const float* Ey    = (const float*)d_in[2];
    const float* WA    = (const float*)d_in[3];
    const float* WO    = (const float*)d_in[4];
    const float* gamma = (const float*)d_in[5];
    const float* beta  = (const float*)d_in[6];

    float* y_out = (float*)d_out;                       // [4096][30000]
    float* A_out = y_out + (size_t)Tok * Yv;            // [8][512][512]

    char* ws = (char*)d_ws;
    size_t off = 0;
    auto alloc = [&](size_t n) { char* p = ws + off; off += (n + 255) & ~(size_t)255; return p; };
    bf16*  Xb    = (bf16*) alloc((size_t)Tok * Dm * 2);
    bf16*  WcatT = (bf16*) alloc((size_t)2 * Dm * Dm * 2);
    bf16*  QXWb  = (bf16*) alloc((size_t)Tok * 1536 * 2);
    bf16*  XWobT = (bf16*) alloc((size_t)Tok * Dm * 2);
    float* Lf    = (float*)alloc((size_t)Tok * Nseq * 4);
    bf16*  Ab    = (bf16*) alloc((size_t)Tok * Nseq * 2);
    float* Qc    = (float*)alloc((size_t)Tok * Dm * 4);
    bf16*  Hb    = (bf16*) alloc((size_t)Tok * Dm * 2);
    bf16*  Eyb   = (bf16*) alloc((size_t)Ypad * Dm * 2);

    // 1. convert + pad E_y
    k_cvt_ey<<<dim3(Ypad), dim3(192), 0, stream>>>(Ey, Eyb);
    // 2. transpose-convert W_A, W_O into packed [1536][768]
    k_wT<<<dim3(24, 24, 2), dim3(32, 8), 0, stream>>>(WA, WO, WcatT);
    // 3. gather embeddings
    k_gather<<<dim3(Tok), dim3(192), 0, stream>>>(Ms, Ev, Xb);
    // 4. [QW | XWo] = X @ [W_A^T; W_O^T]  (bf16 out, N=1536)
    gemm_bt<true><<<dim3(384), dim3(256), 0, stream>>>(
        Xb, WcatT, (void*)QXWb, Tok, 1536, Dm, Dm, 1536, 0L, 0L, 0L);
    // 5. logits = QW @ X^T per batch (f32 out)
    gemm_bt<false><<<dim3(16, 1, 8), dim3(256), 0, stream>>>(
        QXWb, Xb, (void*)Lf, Nseq, Nseq, Dm, 1536, Nseq,
        (long)Nseq * 1536, (long)Nseq * Dm, (long)Nseq * Nseq);
    // 6. bias + mask + softmax -> A (f32 in d_out) and Ab (bf16)
    k_softmax<<<dim3(Tok), dim3(256), 0, stream>>>(Lf, Ms, A_out, Ab);
    // 7. transpose XWo slice per batch
    k_xwoT<<<dim3(16, 24, 8), dim3(32, 8), 0, stream>>>(QXWb, XWobT);
    // 8. Qc = A @ XWo per batch (f32 out)
    gemm_bt<false><<<dim3(24, 1, 8), dim3(256), 0, stream>>>(
        Ab, XWobT, (void*)Qc, Nseq, Dm, Nseq, Nseq, Dm,
        (long)Nseq * Nseq, (long)Dm * Nseq, (long)Nseq * Dm);
    // 9. H = LN(Qc + X)
    k_ln<<<dim3(Tok), dim3(256), 0, stream>>>(Qc, Ms, Ev, gamma, beta, Hb);
    // 10. y_logits = H @ E_y^T  (f32, persistent 256^2 8-phase kernel)
    gemm_big<<<dim3(256), dim3(512), 0, stream>>>(Hb, Eyb, y_out);
}

// Round 5
// 397.927 us; speedup vs baseline: 1.1234x; 1.1234x over previous
//
#include <hip/hip_runtime.h>
#include <hip/hip_bf16.h>

using bf16 = __hip_bfloat16;
typedef __attribute__((ext_vector_type(8))) short bf16x8;
typedef __attribute__((ext_vector_type(4))) float f32x4;

#define DEV __device__ __forceinline__

#define AS1 __attribute__((address_space(1)))
#define AS3 __attribute__((address_space(3)))
#define SB  __builtin_amdgcn_sched_barrier(0)
#define BARR __builtin_amdgcn_s_barrier()
#define LG0 asm volatile("s_waitcnt lgkmcnt(0)" ::: "memory")
#define VM4 asm volatile("s_waitcnt vmcnt(4)" ::: "memory")
#define VM0 asm volatile("s_waitcnt vmcnt(0)" ::: "memory")
#define VM48 asm volatile("s_waitcnt vmcnt(48)" ::: "memory")

// ---------------------------------------------------------------------------
// constants
static constexpr int Bsz = 8, Nseq = 512, Dm = 768, Vv = 30000, Yv = 30000;
static constexpr int Ypad = 30208;               // 118 tiles of 256
static constexpr int NTILE = 118;
static constexpr int TT = 16 * NTILE;            // 1888 output tiles
static constexpr int Tok = Bsz * Nseq;           // 4096
static constexpr int NT = Dm / 64;               // 12 K-tiles of 64

// 16-MFMA cluster for quadrant (MQ,NQ) with B regs BR, setprio-wrapped (T5)
#define MF16(MQ, NQ, BR)                                                      \
    __builtin_amdgcn_s_setprio(1);                                            \
    _Pragma("unroll") for (int mm = 0; mm < 4; ++mm)                          \
    _Pragma("unroll") for (int nn = 0; nn < 2; ++nn) {                        \
        acc[(MQ)*4+mm][(NQ)*2+nn] = __builtin_amdgcn_mfma_f32_16x16x32_bf16(  \
            afr[mm][0], BR[nn][0], acc[(MQ)*4+mm][(NQ)*2+nn], 0, 0, 0);       \
        acc[(MQ)*4+mm][(NQ)*2+nn] = __builtin_amdgcn_mfma_f32_16x16x32_bf16(  \
            afr[mm][1], BR[nn][1], acc[(MQ)*4+mm][(NQ)*2+nn], 0, 0, 0);       \
    }                                                                         \
    __builtin_amdgcn_s_setprio(0);

// ---------------------------------------------------------------------------
// Big GEMM: C[4096][Yv] f32 = A[4096][768]_bf16 * B[Ypad][768]_bf16^T
// Persistent (256 blocks, 1/CU). Block p processes swizzled linear tiles
// {p, p+256, ...} -- exact grid-launch dispatch order (XCD locality, lockstep
// rounds). Tile boundary: next-tile prologue loads -> C-stores -> vmcnt(48)
// (loads retired, stores still in flight, draining under next K-loop).
// Per tile: 256x256, BK=64, 8 waves, 8-phase schedule, 128 KiB LDS.
// Chunks: ci = slot*4 + op*2 + h  (op: A=0,B=1; h: 128-row half; slot: parity)
__global__ __launch_bounds__(512, 2)
void gemm_big(const bf16* __restrict__ Ag, const bf16* __restrict__ Bg,
              float* __restrict__ Cg, float* __restrict__ dump)
{
    __shared__ bf16 sm[8][8192];                 // 8 x 16 KiB = 128 KiB

    const int p = blockIdx.x;
    const int tid  = threadIdx.x;
    const int lane = tid & 63;
    const int wid  = tid >> 6;
    const int wm   = wid >> 2;                   // 0..1
    const int wn   = wid & 3;                    // 0..3

    // staging: thread covers LDS 16B-chunk (l*512+tid); row=c/8, slot8=c&7.
    // swizzle: LDS slot s of row r holds source col-chunk s^(r&7)
    const int lr = tid >> 3;
    const int sc = ((tid & 7) ^ (lr & 7)) << 3;
    const int ldsOff = wid << 9;

    // frag read geometry
    const int fl = lane & 15;
    const int fh = lane >> 4;
    const int e0 = (fh ^ (fl & 7)) << 3;
    const int aro = (wm * 64 + fl) * 64;
    const int bro = (wn * 32 + fl) * 64;

    bf16x8 afr[4][2], b0r[2][2], b1r[2][2];
    f32x4 acc[8][4] = {};
    float* dmp = dump + (size_t)p * 512 + tid;

#define STAGEP(AP, BP, CI, OP, H, TILE)                                        \
    {                                                                          \
        const bf16* _s = ((OP) ? (BP) : (AP)) + (long)(H) * 128 * Dm + (TILE) * 64;\
        __builtin_amdgcn_global_load_lds((const AS1 void*)_s,                  \
            (AS3 void*)&sm[CI][ldsOff], 16, 0, 0);                             \
        __builtin_amdgcn_global_load_lds((const AS1 void*)(_s + (long)64 * Dm),\
            (AS3 void*)&sm[CI][4096 + ldsOff], 16, 0, 0);                      \
    }
#define STAGE(CI, OP, H, TILE) STAGEP(aS, bS, CI, OP, H, TILE)
#define RDA(CI)                                                                \
    _Pragma("unroll") for (int mm = 0; mm < 4; ++mm) {                         \
        afr[mm][0] = *(const bf16x8*)&sm[CI][aro + mm * 1024 + e0];            \
        afr[mm][1] = *(const bf16x8*)&sm[CI][aro + mm * 1024 + (e0 ^ 32)];     \
    }
#define RDB(BR, CI)                                                            \
    _Pragma("unroll") for (int nn = 0; nn < 2; ++nn) {                         \
        BR[nn][0] = *(const bf16x8*)&sm[CI][bro + nn * 1024 + e0];             \
        BR[nn][1] = *(const bf16x8*)&sm[CI][bro + nn * 1024 + (e0 ^ 32)];      \
    }

    // current tile
    int l = p;
    int s0 = (l & 7) * (TT >> 3) + (l >> 3);
    int mT = s0 & 15, nT = s0 >> 4;
    const bf16* aS = Ag + (long)(mT * 256 + lr) * Dm + sc;
    const bf16* bS = Bg + (long)(nT * 256 + lr) * Dm + sc;

    // initial prologue: tile0 {A0,B0,B1,A1} + tile1 {A0,B1}
    STAGE(0, 0, 0, 0) STAGE(2, 1, 0, 0) STAGE(3, 1, 1, 0) STAGE(1, 0, 1, 0)
    STAGE(4, 0, 0, 1) STAGE(7, 1, 1, 1)
    VM4; SB; BARR; SB;

#pragma unroll 1
    while (true) {
#pragma unroll 1
        for (int t = 0; t < NT - 2; t += 2) {
            // p0: quad(0,0) tile t (slot0)
            STAGE(6, 1, 0, t + 1)                // B0 s1
            RDA(0) RDB(b0r, 2)
            SB; BARR; LG0; SB;
            MF16(0, 0, b0r)
            SB; BARR; SB;
            // p1: quad(0,1)
            STAGE(5, 0, 1, t + 1)                // A1 s1
            RDB(b1r, 3)
            SB; BARR; LG0; SB;
            MF16(0, 1, b1r)
            SB; BARR; SB;
            // p2: quad(1,1)
            STAGE(0, 0, 0, t + 2)                // A0 s0
            RDA(1)
            SB; BARR; LG0; SB;
            MF16(1, 1, b1r)
            SB; BARR; SB;
            // p3: quad(1,0) -- LDS-free phase
            STAGE(3, 1, 1, t + 2)                // B1 s0
            VM4; SB; BARR; SB;
            MF16(1, 0, b0r)
            SB; BARR; SB;
            // p4: quad(0,0) tile t+1 (slot1)
            STAGE(2, 1, 0, t + 2)                // B0 s0
            RDA(4) RDB(b0r, 6)
            SB; BARR; LG0; SB;
            MF16(0, 0, b0r)
            SB; BARR; SB;
            // p5: quad(0,1)
            STAGE(1, 0, 1, t + 2)                // A1 s0
            RDB(b1r, 7)
            SB; BARR; LG0; SB;
            MF16(0, 1, b1r)
            SB; BARR; SB;
            // p6: quad(1,1)
            STAGE(4, 0, 0, t + 3)                // A0 s1
            RDA(5)
            SB; BARR; LG0; SB;
            MF16(1, 1, b1r)
            SB; BARR; SB;
            // p7: quad(1,0) -- LDS-free phase
            STAGE(7, 1, 1, t + 3)                // B1 s1
            VM4; SB; BARR; SB;
            MF16(1, 0, b0r)
            SB; BARR; SB;
        }

        // peeled final iter (tiles NT-2, NT-1)
        {
            const int t = NT - 2;
            STAGE(6, 1, 0, t + 1)
            RDA(0) RDB(b0r, 2)
            SB; BARR; LG0; SB;
            MF16(0, 0, b0r)
            SB; BARR; SB;
            STAGE(5, 0, 1, t + 1)
            RDB(b1r, 3)
            SB; BARR; LG0; SB;
            MF16(0, 1, b1r)
            SB; BARR; SB;
            RDA(1)
            SB; BARR; LG0; SB;
            MF16(1, 1, b1r)
            SB; BARR; SB;
            VM0; SB; BARR; SB;
            MF16(1, 0, b0r)
            SB; BARR; SB;
            RDA(4) RDB(b0r, 6)
            SB; BARR; LG0; SB;
            MF16(0, 0, b0r)
            SB; BARR; SB;
            RDB(b1r, 7)
            SB; BARR; LG0; SB;
            MF16(0, 1, b1r)
            SB; BARR; SB;
            RDA(5)
            SB; BARR; LG0; SB;
            MF16(1, 1, b1r)
            SB; BARR; SB;                        // publishes ALL LDS reads
            MF16(1, 0, b0r)                      // regs only
        }

        // ---- tile boundary ----------------------------------------------
        const int l2 = l + 256;
        const bool more = (l2 < TT);
        const int s2 = ((l2 & 7) * (TT >> 3) + (l2 >> 3));
        const int mT2 = s2 & 15, nT2 = s2 >> 4;
        const bf16* aS2 = Ag + (long)(mT2 * 256 + lr) * Dm + sc;
        const bf16* bS2 = Bg + (long)(nT2 * 256 + lr) * Dm + sc;
        if (more) {
            // next-tile prologue FIRST (issue-order: these 12 retire first)
            STAGEP(aS2, bS2, 0, 0, 0, 0) STAGEP(aS2, bS2, 2, 1, 0, 0)
            STAGEP(aS2, bS2, 3, 1, 1, 0) STAGEP(aS2, bS2, 1, 0, 1, 0)
            STAGEP(aS2, bS2, 4, 0, 0, 1) STAGEP(aS2, bS2, 7, 1, 1, 1)
            SB;
        }
        // C-stores (uniform 128 per thread via dump-select; drain under next tile)
        {
            const int rB = mT * 256 + wm * 64 + fh * 4;
            const int cB = nT * 256 + wn * 32 + fl;
#pragma unroll
            for (int mq = 0; mq < 2; ++mq)
#pragma unroll
            for (int mm = 0; mm < 4; ++mm)
#pragma unroll
            for (int nq = 0; nq < 2; ++nq)
#pragma unroll
            for (int nn = 0; nn < 2; ++nn) {
                const int c = cB + nq * 128 + nn * 16;
                const int r = rB + mq * 128 + mm * 16;
                const bool ok = (c < Yv);
#pragma unroll
                for (int j = 0; j < 4; ++j) {
                    float* dst = ok ? (Cg + (long)(r + j) * Yv + c) : dmp;
                    *dst = acc[mq * 4 + mm][nq * 2 + nn][j];
                }
            }
        }
#pragma unroll
        for (int i = 0; i < 8; ++i)
#pragma unroll
            for (int n = 0; n < 4; ++n) acc[i][n] = (f32x4){0.f, 0.f, 0.f, 0.f};
        if (!more) break;                        // kernel end drains stores
        l = l2; mT = mT2; nT = nT2; aS = aS2; bS = bS2;
        SB; VM48; SB; BARR; SB;                  // 12 loads retired; <=48 stores in flight
    }
#undef STAGEP
#undef STAGE
#undef RDA
#undef RDB
}

// ---------------------------------------------------------------------------
// GEMM: C[M][Nc] = A[M][K](lda) * B[Nc][K]^T   (m97-structure, small GEMMs)
template<bool STORE_BF16>
__global__ __launch_bounds__(256)
void gemm_bt(const bf16* __restrict__ Ag, const bf16* __restrict__ Bg,
             void* __restrict__ Cg, int M, int Nc, int K, int lda, int ldc,
             long sA, long sB, long sC)
{
    __shared__ bf16 As[128 * 32];
    __shared__ bf16 Bs[128 * 32];

    const int bz = blockIdx.z;
    const bf16* A  = Ag + (long)bz * sA;
    const bf16* Bm = Bg + (long)bz * sB;

    const int bid = blockIdx.x;
    const int nTilesM = M >> 7;
    const int mTile = bid % nTilesM;
    const int nTile = bid / nTilesM;

    const int tid  = threadIdx.x;
    const int wave = tid >> 6;
    const int lane = tid & 63;

    const int sRow = (wave << 4) + (lane >> 2);
    const int sCol = (lane & 3) << 3;

    const long aBase = (long)(mTile * 128) * lda;
    const long bBase = (long)(nTile * 128) * K;

    const int fl = lane & 15;
    const int fh = lane >> 4;
    const int wRow = (wave >> 1) << 6;
    const int wCol = (wave & 1) << 6;

    f32x4 acc[4][4] = {};

    for (int k0 = 0; k0 < K; k0 += 32) {
#pragma unroll
        for (int t = 0; t < 2; ++t) {
            const bf16* gA = A  + aBase + (long)(t * 64 + sRow) * lda + (k0 + sCol);
            const bf16* gB = Bm + bBase + (long)(t * 64 + sRow) * K + (k0 + sCol);
            bf16* lA = &As[(t * 64 + (wave << 4)) * 32];
            bf16* lB = &Bs[(t * 64 + (wave << 4)) * 32];
            __builtin_amdgcn_global_load_lds(
                (const AS1 void*)gA, (AS3 void*)lA, 16, 0, 0);
            __builtin_amdgcn_global_load_lds(
                (const AS1 void*)gB, (AS3 void*)lB, 16, 0, 0);
        }
        __syncthreads();

        bf16x8 af[4], bfg[4];
#pragma unroll
        for (int m = 0; m < 4; ++m)
            af[m] = *(const bf16x8*)&As[(wRow + m * 16 + fl) * 32 + fh * 8];
#pragma unroll
        for (int n = 0; n < 4; ++n)
            bfg[n] = *(const bf16x8*)&Bs[(wCol + n * 16 + fl) * 32 + fh * 8];
#pragma unroll
        for (int m = 0; m < 4; ++m)
#pragma unroll
            for (int n = 0; n < 4; ++n)
                acc[m][n] = __builtin_amdgcn_mfma_f32_16x16x32_bf16(
                    af[m], bfg[n], acc[m][n], 0, 0, 0);
        __syncthreads();
    }

    const int rBase = mTile * 128 + wRow + fh * 4;
    const int cBase = nTile * 128 + wCol + fl;
#pragma unroll
    for (int m = 0; m < 4; ++m) {
#pragma unroll
        for (int n = 0; n < 4; ++n) {
            int gc = cBase + n * 16;
            int gr = rBase + m * 16;
            if (STORE_BF16) {
                bf16* C = (bf16*)Cg + (long)bz * sC;
#pragma unroll
                for (int j = 0; j < 4; ++j)
                    C[(long)(gr + j) * ldc + gc] = __float2bfloat16(acc[m][n][j]);
            } else {
                float* C = (float*)Cg + (long)bz * sC;
#pragma unroll
                for (int j = 0; j < 4; ++j)
                    C[(long)(gr + j) * ldc + gc] = acc[m][n][j];
            }
        }
    }
}

// ---------------------------------------------------------------------------
// E_y f32 [30000][768] -> bf16 [30208][768], rows >= 30000 zero-filled
__global__ __launch_bounds__(192) void k_cvt_ey(const float* __restrict__ Ey,
                                                bf16* __restrict__ Eyb)
{
    int row = blockIdx.x;
    int d = threadIdx.x * 4;
    union { bf16 h[4]; uint2 u; } pk;
    if (row < Yv) {
        float4 v = *(const float4*)(Ey + (long)row * Dm + d);
        pk.h[0] = __float2bfloat16(v.x); pk.h[1] = __float2bfloat16(v.y);
        pk.h[2] = __float2bfloat16(v.z); pk.h[3] = __float2bfloat16(v.w);
    } else {
        pk.h[0] = pk.h[1] = pk.h[2] = pk.h[3] = __float2bfloat16(0.f);
    }
    *(uint2*)(Eyb + (long)row * Dm + d) = pk.u;
}

// W f32 [768][768] -> Wcat^T bf16 [1536][768]; z=0: W_A rows 0-767, z=1: W_O
__global__ void k_wT(const float* __restrict__ WA, const float* __restrict__ WO,
                     bf16* __restrict__ Wcat)
{
    __shared__ float t[32][33];
    const float* W = blockIdx.z ? WO : WA;
    bf16* WT = Wcat + (size_t)blockIdx.z * Dm * Dm;
    int bx = blockIdx.x * 32;
    int by = blockIdx.y * 32;
    int tx = threadIdx.x, ty = threadIdx.y;
#pragma unroll
    for (int i = 0; i < 32; i += 8)
        t[ty + i][tx] = W[(long)(bx + ty + i) * Dm + (by + tx)];
    __syncthreads();
#pragma unroll
    for (int i = 0; i < 32; i += 8)
        WT[(long)(by + ty + i) * Dm + (bx + tx)] = __float2bfloat16(t[tx][ty + i]);
}

// X = E_v[M_s] -> bf16 [4096][768]
__global__ __launch_bounds__(192) void k_gather(const int* __restrict__ Ms,
                                                const float* __restrict__ Ev,
                                                bf16* __restrict__ Xb)
{
    int token = blockIdx.x;
    int id = Ms[token];
    int d = threadIdx.x * 4;
    float4 v = *(const float4*)(Ev + (long)id * Dm + d);
    union { bf16 h[4]; uint2 u; } pk;
    pk.h[0] = __float2bfloat16(v.x); pk.h[1] = __float2bfloat16(v.y);
    pk.h[2] = __float2bfloat16(v.z); pk.h[3] = __float2bfloat16(v.w);
    *(uint2*)(Xb + (long)token * Dm + d) = pk.u;
}

// XWo slice of QXW bf16 [B][512][1536](+768) -> [B][768][512]
__global__ void k_xwoT(const bf16* __restrict__ Xo, bf16* __restrict__ XoT)
{
    __shared__ bf16 t[32][33];
    int b = blockIdx.z;
    const bf16* src = Xo + (long)b * Nseq * 1536 + 768;
    bf16* dst = XoT + (long)b * Dm * Nseq;
    int bx = blockIdx.x * 32;
    int by = blockIdx.y * 32;
    int tx = threadIdx.x, ty = threadIdx.y;
#pragma unroll
    for (int i = 0; i < 32; i += 8)
        t[ty + i][tx] = src[(long)(bx + ty + i) * 1536 + (by + tx)];
    __syncthreads();
#pragma unroll
    for (int i = 0; i < 32; i += 8)
        dst[(long)(by + ty + i) * Nseq + (bx + tx)] = t[tx][ty + i];
}

// ---------------------------------------------------------------------------
DEV float waveMax(float v) {
#pragma unroll
    for (int o = 32; o > 0; o >>= 1) v = fmaxf(v, __shfl_xor(v, o, 64));
    return v;
}
DEV float waveSum(float v) {
#pragma unroll
    for (int o = 32; o > 0; o >>= 1) v += __shfl_xor(v, o, 64);
    return v;
}

// softmax over j of (L[b,i,j] + (j-i)) with mask; writes A f32 (d_out) + bf16
__global__ __launch_bounds__(256) void k_softmax(const float* __restrict__ L,
                                                 const int* __restrict__ Ms,
                                                 float* __restrict__ Aout,
                                                 bf16* __restrict__ Ab)
{
    __shared__ float red[8];
    int row = blockIdx.x;
    int b = row >> 9, i = row & 511;
    const float* l = L + (long)row * Nseq;
    const int* ms = Ms + (b << 9);
    int t = threadIdx.x;
    int wid = t >> 6, lane = t & 63;
    int j0 = t, j1 = t + 256;

    float a0 = l[j0] + (float)(j0 - i);
    float a1 = l[j1] + (float)(j1 - i);
    if (ms[j0] == 0) a0 = -1e12f;
    if (ms[j1] == 0) a1 = -1e12f;

    float m = waveMax(fmaxf(a0, a1));
    if (lane == 0) red[wid] = m;
    __syncthreads();
    m = fmaxf(fmaxf(red[0], red[1]), fmaxf(red[2], red[3]));

    float e0 = expf(a0 - m), e1 = expf(a1 - m);
    float s = waveSum(e0 + e1);
    if (lane == 0) red[4 + wid] = s;
    __syncthreads();
    s = red[4] + red[5] + red[6] + red[7];
    float inv = 1.0f / s;

    float r0 = e0 * inv, r1 = e1 * inv;
    Aout[(long)row * Nseq + j0] = r0;
    Aout[(long)row * Nseq + j1] = r1;
    Ab[(long)row * Nseq + j0] = __float2bfloat16(r0);
    Ab[(long)row * Nseq + j1] = __float2bfloat16(r1);
}

// H = LN(Qc + E_v[Ms]) * gamma + beta  -> bf16
__global__ __launch_bounds__(256) void k_ln(const float* __restrict__ Qc,
                                            const int* __restrict__ Ms,
                                            const float* __restrict__ Ev,
                                            const float* __restrict__ gamma,
                                            const float* __restrict__ beta,
                                            bf16* __restrict__ Hb)
{
    __shared__ float red[8];
    int row = blockIdx.x;
    int id = Ms[row];
    const float* q = Qc + (long)row * Dm;
    const float* e = Ev + (long)id * Dm;
    int t = threadIdx.x;
    int wid = t >> 6, lane = t & 63;

    float x[3];
#pragma unroll
    for (int c = 0; c < 3; ++c) x[c] = q[t + c * 256] + e[t + c * 256];

    float s = waveSum(x[0] + x[1] + x[2]);
    if (lane == 0) red[wid] = s;
    __syncthreads();
    float mu = (red[0] + red[1] + red[2] + red[3]) * (1.0f / 768.0f);

    float vs = 0.f;
#pragma unroll
    for (int c = 0; c < 3; ++c) { float d = x[c] - mu; vs += d * d; }
    vs = waveSum(vs);
    if (lane == 0) red[4 + wid] = vs;
    __syncthreads();
    float var = (red[4] + red[5] + red[6] + red[7]) * (1.0f / 768.0f);
    float rstd = rsqrtf(var + 1e-5f);

#pragma unroll
    for (int c = 0; c < 3; ++c) {
        int d = t + c * 256;
        Hb[(long)row * Dm + d] =
            __float2bfloat16((x[c] - mu) * rstd * gamma[d] + beta[d]);
    }
}

// ---------------------------------------------------------------------------
extern "C" void kernel_launch(void* const* d_in, const int* in_sizes, int n_in,
                              void* d_out, int out_size, void* d_ws, size_t ws_size,
                              hipStream_t stream)
{
    const int*   Ms    = (const int*)d_in[0];
    const float* Ev    = (const float*)d_in[1];
    const float* Ey    = (const float*)d_in[2];
    const float* WA    = (const float*)d_in[3];
    const float* WO    = (const float*)d_in[4];
    const float* gamma = (const float*)d_in[5];
    const float* beta  = (const float*)d_in[6];

    float* y_out = (float*)d_out;                       // [4096][30000]
    float* A_out = y_out + (size_t)Tok * Yv;            // [8][512][512]

    char* ws = (char*)d_ws;
    size_t off = 0;
    auto alloc = [&](size_t n) { char* p = ws + off; off += (n + 255) & ~(size_t)255; return p; };
    bf16*  Xb    = (bf16*) alloc((size_t)Tok * Dm * 2);
    bf16*  WcatT = (bf16*) alloc((size_t)2 * Dm * Dm * 2);
    bf16*  QXWb  = (bf16*) alloc((size_t)Tok * 1536 * 2);
    bf16*  XWobT = (bf16*) alloc((size_t)Tok * Dm * 2);
    float* Lf    = (float*)alloc((size_t)Tok * Nseq * 4);
    bf16*  Ab    = (bf16*) alloc((size_t)Tok * Nseq * 2);
    float* Qc    = (float*)alloc((size_t)Tok * Dm * 4);
    bf16*  Hb    = (bf16*) alloc((size_t)Tok * Dm * 2);
    bf16*  Eyb   = (bf16*) alloc((size_t)Ypad * Dm * 2);
    float* dump  = (float*)alloc((size_t)256 * 512 * 4);

    // 1. convert + pad E_y
    k_cvt_ey<<<dim3(Ypad), dim3(192), 0, stream>>>(Ey, Eyb);
    // 2. transpose-convert W_A, W_O into packed [1536][768]
    k_wT<<<dim3(24, 24, 2), dim3(32, 8), 0, stream>>>(WA, WO, WcatT);
    // 3. gather embeddings
    k_gather<<<dim3(Tok), dim3(192), 0, stream>>>(Ms, Ev, Xb);
    // 4. [QW | XWo] = X @ [W_A^T; W_O^T]  (bf16 out, N=1536)
    gemm_bt<true><<<dim3(384), dim3(256), 0, stream>>>(
        Xb, WcatT, (void*)QXWb, Tok, 1536, Dm, Dm, 1536, 0L, 0L, 0L);
    // 5. logits = QW @ X^T per batch (f32 out)
    gemm_bt<false><<<dim3(16, 1, 8), dim3(256), 0, stream>>>(
        QXWb, Xb, (void*)Lf, Nseq, Nseq, Dm, 1536, Nseq,
        (long)Nseq * 1536, (long)Nseq * Dm, (long)Nseq * Nseq);
    // 6. bias + mask + softmax -> A (f32 in d_out) and Ab (bf16)
    k_softmax<<<dim3(Tok), dim3(256), 0, stream>>>(Lf, Ms, A_out, Ab);
    // 7. transpose XWo slice per batch
    k_xwoT<<<dim3(16, 24, 8), dim3(32, 8), 0, stream>>>(QXWb, XWobT);
    // 8. Qc = A @ XWo per batch (f32 out)
    gemm_bt<false><<<dim3(24, 1, 8), dim3(256), 0, stream>>>(
        Ab, XWobT, (void*)Qc, Nseq, Dm, Nseq, Nseq, Dm,
        (long)Nseq * Nseq, (long)Dm * Nseq, (long)Nseq * Dm);
    // 9. H = LN(Qc + X)
    k_ln<<<dim3(Tok), dim3(256), 0, stream>>>(Qc, Ms, Ev, gamma, beta, Hb);
    // 10. y_logits = H @ E_y^T  (persistent 256^2 8-phase, store-overlapped)
    gemm_big<<<dim3(256), dim3(512), 0, stream>>>(Hb, Eyb, y_out, dump);
}

// Round 6
// 371.826 us; speedup vs baseline: 1.2022x; 1.0702x over previous
//
#include <hip/hip_runtime.h>
#include <hip/hip_bf16.h>

using bf16 = __hip_bfloat16;
typedef __attribute__((ext_vector_type(8))) short bf16x8;
typedef __attribute__((ext_vector_type(4))) float f32x4;

#define DEV __device__ __forceinline__

#define AS1 __attribute__((address_space(1)))
#define AS3 __attribute__((address_space(3)))
#define SB  __builtin_amdgcn_sched_barrier(0)
#define BARR __builtin_amdgcn_s_barrier()
#define LG0 asm volatile("s_waitcnt lgkmcnt(0)" ::: "memory")
#define VM4 asm volatile("s_waitcnt vmcnt(4)" ::: "memory")
#define VM0 asm volatile("s_waitcnt vmcnt(0)" ::: "memory")
#define VM48 asm volatile("s_waitcnt vmcnt(48)" ::: "memory")

// ---------------------------------------------------------------------------
// constants
static constexpr int Bsz = 8, Nseq = 512, Dm = 768, Vv = 30000, Yv = 30000;
static constexpr int Ypad = 30208;               // 118 tiles of 256
static constexpr int NTILE = 118;
static constexpr int TT = 16 * NTILE;            // 1888 output tiles
static constexpr int Tok = Bsz * Nseq;           // 4096
static constexpr int NT = Dm / 64;               // 12 K-tiles of 64

// 16-MFMA cluster for quadrant (MQ,NQ) with B regs BR, setprio-wrapped (T5)
#define MF16(MQ, NQ, BR)                                                      \
    __builtin_amdgcn_s_setprio(1);                                            \
    _Pragma("unroll") for (int mm = 0; mm < 4; ++mm)                          \
    _Pragma("unroll") for (int nn = 0; nn < 2; ++nn) {                        \
        acc[(MQ)*4+mm][(NQ)*2+nn] = __builtin_amdgcn_mfma_f32_16x16x32_bf16(  \
            afr[mm][0], BR[nn][0], acc[(MQ)*4+mm][(NQ)*2+nn], 0, 0, 0);       \
        acc[(MQ)*4+mm][(NQ)*2+nn] = __builtin_amdgcn_mfma_f32_16x16x32_bf16(  \
            afr[mm][1], BR[nn][1], acc[(MQ)*4+mm][(NQ)*2+nn], 0, 0, 0);       \
    }                                                                         \
    __builtin_amdgcn_s_setprio(0);

// ---------------------------------------------------------------------------
// Big GEMM: C[4096][Yv] f32 = A[4096][768]_bf16 * B[Ypad][768]_bf16^T
// Persistent (256 blocks, 1/CU). XCD-co-located tiles:
//   s = (p&7)*32 + (p>>3) + 256*round  ->  XCD x gets nTiles {2x,2x+1} each
// round (B-panel sharers on ONE L2), mTile = s&15 is round-invariant (fixed
// A-panel per block). Tile boundary: next-tile prologue loads -> nt C-stores
// -> vmcnt(48). Per tile: 256x256, BK=64, 8 waves, 8-phase, 128 KiB LDS.
// Chunks: ci = slot*4 + op*2 + h  (op: A=0,B=1; h: 128-row half; slot: parity)
__global__ __launch_bounds__(512, 2)
void gemm_big(const bf16* __restrict__ Ag, const bf16* __restrict__ Bg,
              float* __restrict__ Cg, float* __restrict__ dump)
{
    __shared__ bf16 sm[8][8192];                 // 8 x 16 KiB = 128 KiB

    const int p = blockIdx.x;
    const int tid  = threadIdx.x;
    const int lane = tid & 63;
    const int wid  = tid >> 6;
    const int wm   = wid >> 2;                   // 0..1
    const int wn   = wid & 3;                    // 0..3

    // staging: thread covers LDS 16B-chunk (l*512+tid); row=c/8, slot8=c&7.
    // swizzle: LDS slot s of row r holds source col-chunk s^(r&7)
    const int lr = tid >> 3;
    const int sc = ((tid & 7) ^ (lr & 7)) << 3;
    const int ldsOff = wid << 9;

    // frag read geometry
    const int fl = lane & 15;
    const int fh = lane >> 4;
    const int e0 = (fh ^ (fl & 7)) << 3;
    const int aro = (wm * 64 + fl) * 64;
    const int bro = (wn * 32 + fl) * 64;

    bf16x8 afr[4][2], b0r[2][2], b1r[2][2];
    f32x4 acc[8][4] = {};
    float* dmp = dump + (size_t)p * 512 + tid;

#define STAGEP(AP, BP, CI, OP, H, TILE)                                        \
    {                                                                          \
        const bf16* _s = ((OP) ? (BP) : (AP)) + (long)(H) * 128 * Dm + (TILE) * 64;\
        __builtin_amdgcn_global_load_lds((const AS1 void*)_s,                  \
            (AS3 void*)&sm[CI][ldsOff], 16, 0, 0);                             \
        __builtin_amdgcn_global_load_lds((const AS1 void*)(_s + (long)64 * Dm),\
            (AS3 void*)&sm[CI][4096 + ldsOff], 16, 0, 0);                      \
    }
#define STAGE(CI, OP, H, TILE) STAGEP(aS, bS, CI, OP, H, TILE)
#define RDA(CI)                                                                \
    _Pragma("unroll") for (int mm = 0; mm < 4; ++mm) {                         \
        afr[mm][0] = *(const bf16x8*)&sm[CI][aro + mm * 1024 + e0];            \
        afr[mm][1] = *(const bf16x8*)&sm[CI][aro + mm * 1024 + (e0 ^ 32)];     \
    }
#define RDB(BR, CI)                                                            \
    _Pragma("unroll") for (int nn = 0; nn < 2; ++nn) {                         \
        BR[nn][0] = *(const bf16x8*)&sm[CI][bro + nn * 1024 + e0];             \
        BR[nn][1] = *(const bf16x8*)&sm[CI][bro + nn * 1024 + (e0 ^ 32)];      \
    }

    // current tile: XCD-chunked swizzle
    int s = (p & 7) * 32 + (p >> 3);             // 0..255
    const int mT = s & 15;                       // round-invariant
    int nT = s >> 4;
    const bf16* aS = Ag + (long)(mT * 256 + lr) * Dm + sc;
    const bf16* bS = Bg + (long)(nT * 256 + lr) * Dm + sc;

    // initial prologue: tile0 {A0,B0,B1,A1} + tile1 {A0,B1}
    STAGE(0, 0, 0, 0) STAGE(2, 1, 0, 0) STAGE(3, 1, 1, 0) STAGE(1, 0, 1, 0)
    STAGE(4, 0, 0, 1) STAGE(7, 1, 1, 1)
    VM4; SB; BARR; SB;

#pragma unroll 1
    while (true) {
#pragma unroll 1
        for (int t = 0; t < NT - 2; t += 2) {
            // p0: quad(0,0) tile t (slot0)
            STAGE(6, 1, 0, t + 1)                // B0 s1
            RDA(0) RDB(b0r, 2)
            SB; BARR; LG0; SB;
            MF16(0, 0, b0r)
            SB; BARR; SB;
            // p1: quad(0,1)
            STAGE(5, 0, 1, t + 1)                // A1 s1
            RDB(b1r, 3)
            SB; BARR; LG0; SB;
            MF16(0, 1, b1r)
            SB; BARR; SB;
            // p2: quad(1,1)
            STAGE(0, 0, 0, t + 2)                // A0 s0
            RDA(1)
            SB; BARR; LG0; SB;
            MF16(1, 1, b1r)
            SB; BARR; SB;
            // p3: quad(1,0) -- LDS-free phase
            STAGE(3, 1, 1, t + 2)                // B1 s0
            VM4; SB; BARR; SB;
            MF16(1, 0, b0r)
            SB; BARR; SB;
            // p4: quad(0,0) tile t+1 (slot1)
            STAGE(2, 1, 0, t + 2)                // B0 s0
            RDA(4) RDB(b0r, 6)
            SB; BARR; LG0; SB;
            MF16(0, 0, b0r)
            SB; BARR; SB;
            // p5: quad(0,1)
            STAGE(1, 0, 1, t + 2)                // A1 s0
            RDB(b1r, 7)
            SB; BARR; LG0; SB;
            MF16(0, 1, b1r)
            SB; BARR; SB;
            // p6: quad(1,1)
            STAGE(4, 0, 0, t + 3)                // A0 s1
            RDA(5)
            SB; BARR; LG0; SB;
            MF16(1, 1, b1r)
            SB; BARR; SB;
            // p7: quad(1,0) -- LDS-free phase
            STAGE(7, 1, 1, t + 3)                // B1 s1
            VM4; SB; BARR; SB;
            MF16(1, 0, b0r)
            SB; BARR; SB;
        }

        // peeled final iter (tiles NT-2, NT-1)
        {
            const int t = NT - 2;
            STAGE(6, 1, 0, t + 1)
            RDA(0) RDB(b0r, 2)
            SB; BARR; LG0; SB;
            MF16(0, 0, b0r)
            SB; BARR; SB;
            STAGE(5, 0, 1, t + 1)
            RDB(b1r, 3)
            SB; BARR; LG0; SB;
            MF16(0, 1, b1r)
            SB; BARR; SB;
            RDA(1)
            SB; BARR; LG0; SB;
            MF16(1, 1, b1r)
            SB; BARR; SB;
            VM0; SB; BARR; SB;
            MF16(1, 0, b0r)
            SB; BARR; SB;
            RDA(4) RDB(b0r, 6)
            SB; BARR; LG0; SB;
            MF16(0, 0, b0r)
            SB; BARR; SB;
            RDB(b1r, 7)
            SB; BARR; LG0; SB;
            MF16(0, 1, b1r)
            SB; BARR; SB;
            RDA(5)
            SB; BARR; LG0; SB;
            MF16(1, 1, b1r)
            SB; BARR; SB;                        // publishes ALL LDS reads
            MF16(1, 0, b0r)                      // regs only
        }

        // ---- tile boundary ----------------------------------------------
        const int s2 = s + 256;
        const bool more = (s2 < TT);
        const int nT2 = s2 >> 4;                 // mT unchanged
        const bf16* bS2 = Bg + (long)(nT2 * 256 + lr) * Dm + sc;
        if (more) {
            // next-tile prologue FIRST (issue-order: these 12 retire first)
            STAGEP(aS, bS2, 0, 0, 0, 0) STAGEP(aS, bS2, 2, 1, 0, 0)
            STAGEP(aS, bS2, 3, 1, 1, 0) STAGEP(aS, bS2, 1, 0, 1, 0)
            STAGEP(aS, bS2, 4, 0, 0, 1) STAGEP(aS, bS2, 7, 1, 1, 1)
            SB;
        }
        // nt C-stores (uniform 128/thread via dump-select; evict-first)
        {
            const int rB = mT * 256 + wm * 64 + fh * 4;
            const int cB = nT * 256 + wn * 32 + fl;
#pragma unroll
            for (int mq = 0; mq < 2; ++mq)
#pragma unroll
            for (int mm = 0; mm < 4; ++mm)
#pragma unroll
            for (int nq = 0; nq < 2; ++nq)
#pragma unroll
            for (int nn = 0; nn < 2; ++nn) {
                const int c = cB + nq * 128 + nn * 16;
                const int r = rB + mq * 128 + mm * 16;
                const bool ok = (c < Yv);
#pragma unroll
                for (int j = 0; j < 4; ++j) {
                    float* dst = ok ? (Cg + (long)(r + j) * Yv + c) : dmp;
                    __builtin_nontemporal_store(acc[mq * 4 + mm][nq * 2 + nn][j], dst);
                }
            }
        }
#pragma unroll
        for (int i = 0; i < 8; ++i)
#pragma unroll
            for (int n = 0; n < 4; ++n) acc[i][n] = (f32x4){0.f, 0.f, 0.f, 0.f};
        if (!more) break;                        // kernel end drains stores
        s = s2; nT = nT2; bS = bS2;
        SB; VM48; SB; BARR; SB;                  // 12 loads retired
    }
#undef STAGEP
#undef STAGE
#undef RDA
#undef RDB
}

// ---------------------------------------------------------------------------
// GEMM: C[M][Nc] = A[M][K](lda) * B[Nc][K]^T   (m97-structure, small GEMMs)
template<bool STORE_BF16>
__global__ __launch_bounds__(256)
void gemm_bt(const bf16* __restrict__ Ag, const bf16* __restrict__ Bg,
             void* __restrict__ Cg, int M, int Nc, int K, int lda, int ldc,
             long sA, long sB, long sC)
{
    __shared__ bf16 As[128 * 32];
    __shared__ bf16 Bs[128 * 32];

    const int bz = blockIdx.z;
    const bf16* A  = Ag + (long)bz * sA;
    const bf16* Bm = Bg + (long)bz * sB;

    const int bid = blockIdx.x;
    const int nTilesM = M >> 7;
    const int mTile = bid % nTilesM;
    const int nTile = bid / nTilesM;

    const int tid  = threadIdx.x;
    const int wave = tid >> 6;
    const int lane = tid & 63;

    const int sRow = (wave << 4) + (lane >> 2);
    const int sCol = (lane & 3) << 3;

    const long aBase = (long)(mTile * 128) * lda;
    const long bBase = (long)(nTile * 128) * K;

    const int fl = lane & 15;
    const int fh = lane >> 4;
    const int wRow = (wave >> 1) << 6;
    const int wCol = (wave & 1) << 6;

    f32x4 acc[4][4] = {};

    for (int k0 = 0; k0 < K; k0 += 32) {
#pragma unroll
        for (int t = 0; t < 2; ++t) {
            const bf16* gA = A  + aBase + (long)(t * 64 + sRow) * lda + (k0 + sCol);
            const bf16* gB = Bm + bBase + (long)(t * 64 + sRow) * K + (k0 + sCol);
            bf16* lA = &As[(t * 64 + (wave << 4)) * 32];
            bf16* lB = &Bs[(t * 64 + (wave << 4)) * 32];
            __builtin_amdgcn_global_load_lds(
                (const AS1 void*)gA, (AS3 void*)lA, 16, 0, 0);
            __builtin_amdgcn_global_load_lds(
                (const AS1 void*)gB, (AS3 void*)lB, 16, 0, 0);
        }
        __syncthreads();

        bf16x8 af[4], bfg[4];
#pragma unroll
        for (int m = 0; m < 4; ++m)
            af[m] = *(const bf16x8*)&As[(wRow + m * 16 + fl) * 32 + fh * 8];
#pragma unroll
        for (int n = 0; n < 4; ++n)
            bfg[n] = *(const bf16x8*)&Bs[(wCol + n * 16 + fl) * 32 + fh * 8];
#pragma unroll
        for (int m = 0; m < 4; ++m)
#pragma unroll
            for (int n = 0; n < 4; ++n)
                acc[m][n] = __builtin_amdgcn_mfma_f32_16x16x32_bf16(
                    af[m], bfg[n], acc[m][n], 0, 0, 0);
        __syncthreads();
    }

    const int rBase = mTile * 128 + wRow + fh * 4;
    const int cBase = nTile * 128 + wCol + fl;
#pragma unroll
    for (int m = 0; m < 4; ++m) {
#pragma unroll
        for (int n = 0; n < 4; ++n) {
            int gc = cBase + n * 16;
            int gr = rBase + m * 16;
            if (STORE_BF16) {
                bf16* C = (bf16*)Cg + (long)bz * sC;
#pragma unroll
                for (int j = 0; j < 4; ++j)
                    C[(long)(gr + j) * ldc + gc] = __float2bfloat16(acc[m][n][j]);
            } else {
                float* C = (float*)Cg + (long)bz * sC;
#pragma unroll
                for (int j = 0; j < 4; ++j)
                    C[(long)(gr + j) * ldc + gc] = acc[m][n][j];
            }
        }
    }
}

// ---------------------------------------------------------------------------
// E_y f32 [30000][768] -> bf16 [30208][768], rows >= 30000 zero-filled.
// Flat vectorized: 8 elems/thread (768 % 8 == 0, no row straddle).
__global__ __launch_bounds__(256) void k_cvt_ey(const float* __restrict__ Ey,
                                                bf16* __restrict__ Eyb)
{
    const long idx = ((long)blockIdx.x * 256 + threadIdx.x) * 8;
    const int row = (int)(idx / Dm);
    union { bf16 h[8]; uint4 u; } pk;
    if (row < Yv) {
        const f32x4* s = (const f32x4*)(Ey + idx);
        f32x4 a = __builtin_nontemporal_load(s);
        f32x4 b = __builtin_nontemporal_load(s + 1);
#pragma unroll
        for (int i = 0; i < 4; ++i) {
            pk.h[i]     = __float2bfloat16(a[i]);
            pk.h[4 + i] = __float2bfloat16(b[i]);
        }
    } else {
#pragma unroll
        for (int i = 0; i < 8; ++i) pk.h[i] = __float2bfloat16(0.f);
    }
    *(uint4*)(Eyb + idx) = pk.u;
}

// W f32 [768][768] -> Wcat^T bf16 [1536][768]; z=0: W_A rows 0-767, z=1: W_O
__global__ void k_wT(const float* __restrict__ WA, const float* __restrict__ WO,
                     bf16* __restrict__ Wcat)
{
    __shared__ float t[32][33];
    const float* W = blockIdx.z ? WO : WA;
    bf16* WT = Wcat + (size_t)blockIdx.z * Dm * Dm;
    int bx = blockIdx.x * 32;
    int by = blockIdx.y * 32;
    int tx = threadIdx.x, ty = threadIdx.y;
#pragma unroll
    for (int i = 0; i < 32; i += 8)
        t[ty + i][tx] = W[(long)(bx + ty + i) * Dm + (by + tx)];
    __syncthreads();
#pragma unroll
    for (int i = 0; i < 32; i += 8)
        WT[(long)(by + ty + i) * Dm + (bx + tx)] = __float2bfloat16(t[tx][ty + i]);
}

// X = E_v[M_s] -> bf16 [4096][768]
__global__ __launch_bounds__(192) void k_gather(const int* __restrict__ Ms,
                                                const float* __restrict__ Ev,
                                                bf16* __restrict__ Xb)
{
    int token = blockIdx.x;
    int id = Ms[token];
    int d = threadIdx.x * 4;
    float4 v = *(const float4*)(Ev + (long)id * Dm + d);
    union { bf16 h[4]; uint2 u; } pk;
    pk.h[0] = __float2bfloat16(v.x); pk.h[1] = __float2bfloat16(v.y);
    pk.h[2] = __float2bfloat16(v.z); pk.h[3] = __float2bfloat16(v.w);
    *(uint2*)(Xb + (long)token * Dm + d) = pk.u;
}

// XWo slice of QXW bf16 [B][512][1536](+768) -> [B][768][512]
__global__ void k_xwoT(const bf16* __restrict__ Xo, bf16* __restrict__ XoT)
{
    __shared__ bf16 t[32][33];
    int b = blockIdx.z;
    const bf16* src = Xo + (long)b * Nseq * 1536 + 768;
    bf16* dst = XoT + (long)b * Dm * Nseq;
    int bx = blockIdx.x * 32;
    int by = blockIdx.y * 32;
    int tx = threadIdx.x, ty = threadIdx.y;
#pragma unroll
    for (int i = 0; i < 32; i += 8)
        t[ty + i][tx] = src[(long)(bx + ty + i) * 1536 + (by + tx)];
    __syncthreads();
#pragma unroll
    for (int i = 0; i < 32; i += 8)
        dst[(long)(by + ty + i) * Nseq + (bx + tx)] = t[tx][ty + i];
}

// ---------------------------------------------------------------------------
DEV float waveMax(float v) {
#pragma unroll
    for (int o = 32; o > 0; o >>= 1) v = fmaxf(v, __shfl_xor(v, o, 64));
    return v;
}
DEV float waveSum(float v) {
#pragma unroll
    for (int o = 32; o > 0; o >>= 1) v += __shfl_xor(v, o, 64);
    return v;
}

// softmax over j of (L[b,i,j] + (j-i)) with mask; writes A f32 (d_out) + bf16
__global__ __launch_bounds__(256) void k_softmax(const float* __restrict__ L,
                                                 const int* __restrict__ Ms,
                                                 float* __restrict__ Aout,
                                                 bf16* __restrict__ Ab)
{
    __shared__ float red[8];
    int row = blockIdx.x;
    int b = row >> 9, i = row & 511;
    const float* l = L + (long)row * Nseq;
    const int* ms = Ms + (b << 9);
    int t = threadIdx.x;
    int wid = t >> 6, lane = t & 63;
    int j0 = t, j1 = t + 256;

    float a0 = l[j0] + (float)(j0 - i);
    float a1 = l[j1] + (float)(j1 - i);
    if (ms[j0] == 0) a0 = -1e12f;
    if (ms[j1] == 0) a1 = -1e12f;

    float m = waveMax(fmaxf(a0, a1));
    if (lane == 0) red[wid] = m;
    __syncthreads();
    m = fmaxf(fmaxf(red[0], red[1]), fmaxf(red[2], red[3]));

    float e0 = expf(a0 - m), e1 = expf(a1 - m);
    float s = waveSum(e0 + e1);
    if (lane == 0) red[4 + wid] = s;
    __syncthreads();
    s = red[4] + red[5] + red[6] + red[7];
    float inv = 1.0f / s;

    float r0 = e0 * inv, r1 = e1 * inv;
    __builtin_nontemporal_store(r0, &Aout[(long)row * Nseq + j0]);
    __builtin_nontemporal_store(r1, &Aout[(long)row * Nseq + j1]);
    Ab[(long)row * Nseq + j0] = __float2bfloat16(r0);
    Ab[(long)row * Nseq + j1] = __float2bfloat16(r1);
}

// H = LN(Qc + E_v[Ms]) * gamma + beta  -> bf16
__global__ __launch_bounds__(256) void k_ln(const float* __restrict__ Qc,
                                            const int* __restrict__ Ms,
                                            const float* __restrict__ Ev,
                                            const float* __restrict__ gamma,
                                            const float* __restrict__ beta,
                                            bf16* __restrict__ Hb)
{
    __shared__ float red[8];
    int row = blockIdx.x;
    int id = Ms[row];
    const float* q = Qc + (long)row * Dm;
    const float* e = Ev + (long)id * Dm;
    int t = threadIdx.x;
    int wid = t >> 6, lane = t & 63;

    float x[3];
#pragma unroll
    for (int c = 0; c < 3; ++c) x[c] = q[t + c * 256] + e[t + c * 256];

    float s = waveSum(x[0] + x[1] + x[2]);
    if (lane == 0) red[wid] = s;
    __syncthreads();
    float mu = (red[0] + red[1] + red[2] + red[3]) * (1.0f / 768.0f);

    float vs = 0.f;
#pragma unroll
    for (int c = 0; c < 3; ++c) { float d = x[c] - mu; vs += d * d; }
    vs = waveSum(vs);
    if (lane == 0) red[4 + wid] = vs;
    __syncthreads();
    float var = (red[4] + red[5] + red[6] + red[7]) * (1.0f / 768.0f);
    float rstd = rsqrtf(var + 1e-5f);

#pragma unroll
    for (int c = 0; c < 3; ++c) {
        int d = t + c * 256;
        Hb[(long)row * Dm + d] =
            __float2bfloat16((x[c] - mu) * rstd * gamma[d] + beta[d]);
    }
}

// ---------------------------------------------------------------------------
extern "C" void kernel_launch(void* const* d_in, const int* in_sizes, int n_in,
                              void* d_out, int out_size, void* d_ws, size_t ws_size,
                              hipStream_t stream)
{
    const int*   Ms    = (const int*)d_in[0];
    const float* Ev    = (const float*)d_in[1];
    const float* Ey    = (const float*)d_in[2];
    const float* WA    = (const float*)d_in[3];
    const float* WO    = (const float*)d_in[4];
    const float* gamma = (const float*)d_in[5];
    const float* beta  = (const float*)d_in[6];

    float* y_out = (float*)d_out;                       // [4096][30000]
    float* A_out = y_out + (size_t)Tok * Yv;            // [8][512][512]

    char* ws = (char*)d_ws;
    size_t off = 0;
    auto alloc = [&](size_t n) { char* p = ws + off; off += (n + 255) & ~(size_t)255; return p; };
    bf16*  Xb    = (bf16*) alloc((size_t)Tok * Dm * 2);
    bf16*  WcatT = (bf16*) alloc((size_t)2 * Dm * Dm * 2);
    bf16*  QXWb  = (bf16*) alloc((size_t)Tok * 1536 * 2);
    bf16*  XWobT = (bf16*) alloc((size_t)Tok * Dm * 2);
    float* Lf    = (float*)alloc((size_t)Tok * Nseq * 4);
    bf16*  Ab    = (bf16*) alloc((size_t)Tok * Nseq * 2);
    float* Qc    = (float*)alloc((size_t)Tok * Dm * 4);
    bf16*  Hb    = (bf16*) alloc((size_t)Tok * Dm * 2);
    bf16*  Eyb   = (bf16*) alloc((size_t)Ypad * Dm * 2);
    float* dump  = (float*)alloc((size_t)256 * 512 * 4);

    // 1. convert + pad E_y (flat, 8 elems/thread: 30208*768/2048 = 11328 blocks)
    k_cvt_ey<<<dim3(11328), dim3(256), 0, stream>>>(Ey, Eyb);
    // 2. transpose-convert W_A, W_O into packed [1536][768]
    k_wT<<<dim3(24, 24, 2), dim3(32, 8), 0, stream>>>(WA, WO, WcatT);
    // 3. gather embeddings
    k_gather<<<dim3(Tok), dim3(192), 0, stream>>>(Ms, Ev, Xb);
    // 4. [QW | XWo] = X @ [W_A^T; W_O^T]  (bf16 out, N=1536)
    gemm_bt<true><<<dim3(384), dim3(256), 0, stream>>>(
        Xb, WcatT, (void*)QXWb, Tok, 1536, Dm, Dm, 1536, 0L, 0L, 0L);
    // 5. logits = QW @ X^T per batch (f32 out)
    gemm_bt<false><<<dim3(16, 1, 8), dim3(256), 0, stream>>>(
        QXWb, Xb, (void*)Lf, Nseq, Nseq, Dm, 1536, Nseq,
        (long)Nseq * 1536, (long)Nseq * Dm, (long)Nseq * Nseq);
    // 6. bias + mask + softmax -> A (f32 in d_out, nt) and Ab (bf16)
    k_softmax<<<dim3(Tok), dim3(256), 0, stream>>>(Lf, Ms, A_out, Ab);
    // 7. transpose XWo slice per batch
    k_xwoT<<<dim3(16, 24, 8), dim3(32, 8), 0, stream>>>(QXWb, XWobT);
    // 8. Qc = A @ XWo per batch (f32 out)
    gemm_bt<false><<<dim3(24, 1, 8), dim3(256), 0, stream>>>(
        Ab, XWobT, (void*)Qc, Nseq, Dm, Nseq, Nseq, Dm,
        (long)Nseq * Nseq, (long)Dm * Nseq, (long)Nseq * Dm);
    // 9. H = LN(Qc + X)
    k_ln<<<dim3(Tok), dim3(256), 0, stream>>>(Qc, Ms, Ev, gamma, beta, Hb);
    // 10. y_logits = H @ E_y^T  (persistent XCD-co-located 256^2 8-phase, nt stores)
    gemm_big<<<dim3(256), dim3(512), 0, stream>>>(Hb, Eyb, y_out, dump);
}

// Round 7
// 361.720 us; speedup vs baseline: 1.2358x; 1.0279x over previous
//
#include <hip/hip_runtime.h>
#include <hip/hip_bf16.h>

using bf16 = __hip_bfloat16;
typedef __attribute__((ext_vector_type(8))) short bf16x8;
typedef __attribute__((ext_vector_type(4))) float f32x4;

#define DEV __device__ __forceinline__

#define AS1 __attribute__((address_space(1)))
#define AS3 __attribute__((address_space(3)))
#define SB  __builtin_amdgcn_sched_barrier(0)
#define BARR __builtin_amdgcn_s_barrier()
#define LG0 asm volatile("s_waitcnt lgkmcnt(0)" ::: "memory")
#define VM3 asm volatile("s_waitcnt vmcnt(3)" ::: "memory")
#define VM1 asm volatile("s_waitcnt vmcnt(1)" ::: "memory")
#define VM0 asm volatile("s_waitcnt vmcnt(0)" ::: "memory")

// ---------------------------------------------------------------------------
// constants
static constexpr int Bsz = 8, Nseq = 512, Dm = 768, Vv = 30000, Yv = 30000;
static constexpr int Ypad = 30208;               // 118 tiles of 256
static constexpr int Tok = Bsz * Nseq;           // 4096
static constexpr int NT = Dm / 32;               // 24 K-tiles of 32

// ---------------------------------------------------------------------------
// Big GEMM: C[4096][Yv] f32 = A[4096][768]_bf16 * B[Ypad][768]_bf16^T
// 128M x 256N tile, BK=32, 8 waves (2x4), 48 KiB LDS -> 2 blocks/CU
// (__launch_bounds__(512,4) caps VGPR<=128). 4-phase/iter (2 K-tiles),
// 6 chunks {A,B0,B1} x 2 slots of 8KB, 1 gload_lds/thread/chunk,
// vmcnt(3) counted waits, 3-phase prefetch lead. Grid 3776, XCD swizzle.
__global__ __launch_bounds__(512, 4)
void gemm_big(const bf16* __restrict__ Ag, const bf16* __restrict__ Bg,
              float* __restrict__ Cg)
{
    __shared__ bf16 sm[6][4096];                 // 6 x 8 KiB = 48 KiB

    int bid = blockIdx.x;
    { int cpx = gridDim.x >> 3; bid = (bid & 7) * cpx + (bid >> 3); }
    const int mT = bid & 31;                     // 32 consecutive share B-panel
    const int nT = bid >> 5;                     // 0..117

    const int tid  = threadIdx.x;
    const int lane = tid & 63;
    const int wid  = tid >> 6;
    const int wm   = wid >> 2;                   // 0..1 -> 64-row half
    const int wn   = wid & 3;                    // 0..3 -> 32-col slice

    // staging: thread covers 16B at chunk elem tid*8: row lr=tid>>2, slot tid&3
    // swizzle: LDS slot s of row r holds source k-chunk s^(r&3)
    const int lr = tid >> 2;                     // 0..127
    const int sc = ((tid & 3) ^ (lr & 3)) << 3;  // 0/8/16/24
    const bf16* aS  = Ag + (long)(mT * 128 + lr) * Dm + sc;
    const bf16* bS0 = Bg + (long)(nT * 256 + lr) * Dm + sc;
    const bf16* bS1 = bS0 + (long)128 * Dm;
    const int ldsW = wid << 9;                   // elems, +lane*8 implicit

    // frag read geometry: row*32 + ((fh^(row&3))<<3), row&3 == fl&3
    const int fl = lane & 15;
    const int fh = lane >> 4;
    const int e0 = (fh ^ (fl & 3)) << 3;
    const int aro = (wm * 64 + fl) * 32;
    const int bro = (wn * 32 + fl) * 32;

    bf16x8 afr[4], bfr[2];
    f32x4 acc[4][2][2] = {};

#define STG(CI, PTR, T)                                                        \
    __builtin_amdgcn_global_load_lds((const AS1 void*)((PTR) + (T) * 32),      \
        (AS3 void*)&sm[CI][ldsW], 16, 0, 0);
#define RA(CI)                                                                 \
    _Pragma("unroll") for (int mm = 0; mm < 4; ++mm)                           \
        afr[mm] = *(const bf16x8*)&sm[CI][aro + mm * 512 + e0];
#define RB(CI)                                                                 \
    _Pragma("unroll") for (int nn = 0; nn < 2; ++nn)                           \
        bfr[nn] = *(const bf16x8*)&sm[CI][bro + nn * 512 + e0];
#define MF8(NQ)                                                                \
    __builtin_amdgcn_s_setprio(1);                                             \
    _Pragma("unroll") for (int mm = 0; mm < 4; ++mm)                           \
    _Pragma("unroll") for (int nn = 0; nn < 2; ++nn)                           \
        acc[mm][NQ][nn] = __builtin_amdgcn_mfma_f32_16x16x32_bf16(             \
            afr[mm], bfr[nn], acc[mm][NQ][nn], 0, 0, 0);                       \
    __builtin_amdgcn_s_setprio(0);

    // prologue: tile0 {A,B0,B1} + tile1 {A,B0}; confirm c0,c1 (5 outstanding)
    STG(0, aS, 0) STG(1, bS0, 0) STG(2, bS1, 0) STG(3, aS, 1) STG(4, bS0, 1)
    VM3; SB; BARR; SB;

    // main loop: iters t = 0,2,...,20 (11); peeled t=22
    // chunk lifecycle per iter: reads P0:{c0,c1} P1:{c2} P2:{c3,c4} P3:{c5}
    // stages            per iter:       P0:{c5<-t+1} P1:{c0,c1<-t+2} P2:{c2<-t+2} P3:{c3,c4<-t+3}
#pragma unroll 1
    for (int t = 0; t < NT - 2; t += 2) {
        // P0: K-tile t, nq=0
        RA(0) RB(1)
        STG(5, bS1, t + 1)
        VM3; SB; BARR; LG0; SB;
        MF8(0)
        SB; BARR; SB;
        // P1: K-tile t, nq=1
        RB(2)
        STG(0, aS, t + 2) STG(1, bS0, t + 2)
        VM3; SB; BARR; LG0; SB;
        MF8(1)
        SB; BARR; SB;
        // P2: K-tile t+1, nq=0
        RA(3) RB(4)
        STG(2, bS1, t + 2)
        VM3; SB; BARR; LG0; SB;
        MF8(0)
        SB; BARR; SB;
        // P3: K-tile t+1, nq=1
        RB(5)
        STG(3, aS, t + 3) STG(4, bS0, t + 3)
        VM3; SB; BARR; LG0; SB;
        MF8(1)
        SB; BARR; SB;
    }

    // peeled final iter (K-tiles 22,23): only P0 stages (c5 <- tile 23 B1)
    {
        RA(0) RB(1)
        STG(5, bS1, NT - 1)
        VM3; SB; BARR; LG0; SB;                  // confirms c2
        MF8(0)
        SB; BARR; SB;
        RB(2)
        VM1; SB; BARR; LG0; SB;                  // confirms c3,c4
        MF8(1)
        SB; BARR; SB;
        RA(3) RB(4)
        VM0; SB; BARR; LG0; SB;                  // confirms c5
        MF8(0)
        SB; BARR; SB;
        RB(5)
        SB; BARR; LG0; SB;
        MF8(1)
    }

    // epilogue: nt dword stores; drain overlaps the co-resident block
    const int rB = mT * 128 + wm * 64 + fh * 4;
    const int cB = nT * 256 + wn * 32 + fl;
#pragma unroll
    for (int mm = 0; mm < 4; ++mm)
#pragma unroll
    for (int nq = 0; nq < 2; ++nq)
#pragma unroll
    for (int nn = 0; nn < 2; ++nn) {
        const int c = cB + nq * 128 + nn * 16;
        if (c >= Yv) continue;
        const int r = rB + mm * 16;
#pragma unroll
        for (int j = 0; j < 4; ++j)
            __builtin_nontemporal_store(acc[mm][nq][nn][j],
                                        Cg + (long)(r + j) * Yv + c);
    }
#undef STG
#undef RA
#undef RB
#undef MF8
}

// ---------------------------------------------------------------------------
// GEMM: C[M][Nc] = A[M][K](lda) * B[Nc][K]^T   (m97-structure, small GEMMs)
template<bool STORE_BF16>
__global__ __launch_bounds__(256)
void gemm_bt(const bf16* __restrict__ Ag, const bf16* __restrict__ Bg,
             void* __restrict__ Cg, int M, int Nc, int K, int lda, int ldc,
             long sA, long sB, long sC)
{
    __shared__ bf16 As[128 * 32];
    __shared__ bf16 Bs[128 * 32];

    const int bz = blockIdx.z;
    const bf16* A  = Ag + (long)bz * sA;
    const bf16* Bm = Bg + (long)bz * sB;

    const int bid = blockIdx.x;
    const int nTilesM = M >> 7;
    const int mTile = bid % nTilesM;
    const int nTile = bid / nTilesM;

    const int tid  = threadIdx.x;
    const int wave = tid >> 6;
    const int lane = tid & 63;

    const int sRow = (wave << 4) + (lane >> 2);
    const int sCol = (lane & 3) << 3;

    const long aBase = (long)(mTile * 128) * lda;
    const long bBase = (long)(nTile * 128) * K;

    const int fl = lane & 15;
    const int fh = lane >> 4;
    const int wRow = (wave >> 1) << 6;
    const int wCol = (wave & 1) << 6;

    f32x4 acc[4][4] = {};

    for (int k0 = 0; k0 < K; k0 += 32) {
#pragma unroll
        for (int t = 0; t < 2; ++t) {
            const bf16* gA = A  + aBase + (long)(t * 64 + sRow) * lda + (k0 + sCol);
            const bf16* gB = Bm + bBase + (long)(t * 64 + sRow) * K + (k0 + sCol);
            bf16* lA = &As[(t * 64 + (wave << 4)) * 32];
            bf16* lB = &Bs[(t * 64 + (wave << 4)) * 32];
            __builtin_amdgcn_global_load_lds(
                (const AS1 void*)gA, (AS3 void*)lA, 16, 0, 0);
            __builtin_amdgcn_global_load_lds(
                (const AS1 void*)gB, (AS3 void*)lB, 16, 0, 0);
        }
        __syncthreads();

        bf16x8 af[4], bfg[4];
#pragma unroll
        for (int m = 0; m < 4; ++m)
            af[m] = *(const bf16x8*)&As[(wRow + m * 16 + fl) * 32 + fh * 8];
#pragma unroll
        for (int n = 0; n < 4; ++n)
            bfg[n] = *(const bf16x8*)&Bs[(wCol + n * 16 + fl) * 32 + fh * 8];
#pragma unroll
        for (int m = 0; m < 4; ++m)
#pragma unroll
            for (int n = 0; n < 4; ++n)
                acc[m][n] = __builtin_amdgcn_mfma_f32_16x16x32_bf16(
                    af[m], bfg[n], acc[m][n], 0, 0, 0);
        __syncthreads();
    }

    const int rBase = mTile * 128 + wRow + fh * 4;
    const int cBase = nTile * 128 + wCol + fl;
#pragma unroll
    for (int m = 0; m < 4; ++m) {
#pragma unroll
        for (int n = 0; n < 4; ++n) {
            int gc = cBase + n * 16;
            int gr = rBase + m * 16;
            if (STORE_BF16) {
                bf16* C = (bf16*)Cg + (long)bz * sC;
#pragma unroll
                for (int j = 0; j < 4; ++j)
                    C[(long)(gr + j) * ldc + gc] = __float2bfloat16(acc[m][n][j]);
            } else {
                float* C = (float*)Cg + (long)bz * sC;
#pragma unroll
                for (int j = 0; j < 4; ++j)
                    C[(long)(gr + j) * ldc + gc] = acc[m][n][j];
            }
        }
    }
}

// ---------------------------------------------------------------------------
// E_y f32 [30000][768] -> bf16 [30208][768], rows >= 30000 zero-filled.
__global__ __launch_bounds__(256) void k_cvt_ey(const float* __restrict__ Ey,
                                                bf16* __restrict__ Eyb)
{
    const long idx = ((long)blockIdx.x * 256 + threadIdx.x) * 8;
    const int row = (int)(idx / Dm);
    union { bf16 h[8]; uint4 u; } pk;
    if (row < Yv) {
        const f32x4* s = (const f32x4*)(Ey + idx);
        f32x4 a = __builtin_nontemporal_load(s);
        f32x4 b = __builtin_nontemporal_load(s + 1);
#pragma unroll
        for (int i = 0; i < 4; ++i) {
            pk.h[i]     = __float2bfloat16(a[i]);
            pk.h[4 + i] = __float2bfloat16(b[i]);
        }
    } else {
#pragma unroll
        for (int i = 0; i < 8; ++i) pk.h[i] = __float2bfloat16(0.f);
    }
    *(uint4*)(Eyb + idx) = pk.u;
}

// W f32 [768][768] -> Wcat^T bf16 [1536][768]; z=0: W_A rows 0-767, z=1: W_O
__global__ void k_wT(const float* __restrict__ WA, const float* __restrict__ WO,
                     bf16* __restrict__ Wcat)
{
    __shared__ float t[32][33];
    const float* W = blockIdx.z ? WO : WA;
    bf16* WT = Wcat + (size_t)blockIdx.z * Dm * Dm;
    int bx = blockIdx.x * 32;
    int by = blockIdx.y * 32;
    int tx = threadIdx.x, ty = threadIdx.y;
#pragma unroll
    for (int i = 0; i < 32; i += 8)
        t[ty + i][tx] = W[(long)(bx + ty + i) * Dm + (by + tx)];
    __syncthreads();
#pragma unroll
    for (int i = 0; i < 32; i += 8)
        WT[(long)(by + ty + i) * Dm + (bx + tx)] = __float2bfloat16(t[tx][ty + i]);
}

// X = E_v[M_s] -> bf16 [4096][768]
__global__ __launch_bounds__(192) void k_gather(const int* __restrict__ Ms,
                                                const float* __restrict__ Ev,
                                                bf16* __restrict__ Xb)
{
    int token = blockIdx.x;
    int id = Ms[token];
    int d = threadIdx.x * 4;
    float4 v = *(const float4*)(Ev + (long)id * Dm + d);
    union { bf16 h[4]; uint2 u; } pk;
    pk.h[0] = __float2bfloat16(v.x); pk.h[1] = __float2bfloat16(v.y);
    pk.h[2] = __float2bfloat16(v.z); pk.h[3] = __float2bfloat16(v.w);
    *(uint2*)(Xb + (long)token * Dm + d) = pk.u;
}

// XWo slice of QXW bf16 [B][512][1536](+768) -> [B][768][512]
__global__ void k_xwoT(const bf16* __restrict__ Xo, bf16* __restrict__ XoT)
{
    __shared__ bf16 t[32][33];
    int b = blockIdx.z;
    const bf16* src = Xo + (long)b * Nseq * 1536 + 768;
    bf16* dst = XoT + (long)b * Dm * Nseq;
    int bx = blockIdx.x * 32;
    int by = blockIdx.y * 32;
    int tx = threadIdx.x, ty = threadIdx.y;
#pragma unroll
    for (int i = 0; i < 32; i += 8)
        t[ty + i][tx] = src[(long)(bx + ty + i) * 1536 + (by + tx)];
    __syncthreads();
#pragma unroll
    for (int i = 0; i < 32; i += 8)
        dst[(long)(by + ty + i) * Nseq + (bx + tx)] = t[tx][ty + i];
}

// ---------------------------------------------------------------------------
DEV float waveMax(float v) {
#pragma unroll
    for (int o = 32; o > 0; o >>= 1) v = fmaxf(v, __shfl_xor(v, o, 64));
    return v;
}
DEV float waveSum(float v) {
#pragma unroll
    for (int o = 32; o > 0; o >>= 1) v += __shfl_xor(v, o, 64);
    return v;
}

// softmax over j of (L[b,i,j] + (j-i)) with mask; writes A f32 (d_out) + bf16
__global__ __launch_bounds__(256) void k_softmax(const float* __restrict__ L,
                                                 const int* __restrict__ Ms,
                                                 float* __restrict__ Aout,
                                                 bf16* __restrict__ Ab)
{
    __shared__ float red[8];
    int row = blockIdx.x;
    int b = row >> 9, i = row & 511;
    const float* l = L + (long)row * Nseq;
    const int* ms = Ms + (b << 9);
    int t = threadIdx.x;
    int wid = t >> 6, lane = t & 63;
    int j0 = t, j1 = t + 256;

    float a0 = l[j0] + (float)(j0 - i);
    float a1 = l[j1] + (float)(j1 - i);
    if (ms[j0] == 0) a0 = -1e12f;
    if (ms[j1] == 0) a1 = -1e12f;

    float m = waveMax(fmaxf(a0, a1));
    if (lane == 0) red[wid] = m;
    __syncthreads();
    m = fmaxf(fmaxf(red[0], red[1]), fmaxf(red[2], red[3]));

    float e0 = expf(a0 - m), e1 = expf(a1 - m);
    float s = waveSum(e0 + e1);
    if (lane == 0) red[4 + wid] = s;
    __syncthreads();
    s = red[4] + red[5] + red[6] + red[7];
    float inv = 1.0f / s;

    float r0 = e0 * inv, r1 = e1 * inv;
    __builtin_nontemporal_store(r0, &Aout[(long)row * Nseq + j0]);
    __builtin_nontemporal_store(r1, &Aout[(long)row * Nseq + j1]);
    Ab[(long)row * Nseq + j0] = __float2bfloat16(r0);
    Ab[(long)row * Nseq + j1] = __float2bfloat16(r1);
}

// H = LN(Qc + E_v[Ms]) * gamma + beta  -> bf16
__global__ __launch_bounds__(256) void k_ln(const float* __restrict__ Qc,
                                            const int* __restrict__ Ms,
                                            const float* __restrict__ Ev,
                                            const float* __restrict__ gamma,
                                            const float* __restrict__ beta,
                                            bf16* __restrict__ Hb)
{
    __shared__ float red[8];
    int row = blockIdx.x;
    int id = Ms[row];
    const float* q = Qc + (long)row * Dm;
    const float* e = Ev + (long)id * Dm;
    int t = threadIdx.x;
    int wid = t >> 6, lane = t & 63;

    float x[3];
#pragma unroll
    for (int c = 0; c < 3; ++c) x[c] = q[t + c * 256] + e[t + c * 256];

    float s = waveSum(x[0] + x[1] + x[2]);
    if (lane == 0) red[wid] = s;
    __syncthreads();
    float mu = (red[0] + red[1] + red[2] + red[3]) * (1.0f / 768.0f);

    float vs = 0.f;
#pragma unroll
    for (int c = 0; c < 3; ++c) { float d = x[c] - mu; vs += d * d; }
    vs = waveSum(vs);
    if (lane == 0) red[4 + wid] = vs;
    __syncthreads();
    float var = (red[4] + red[5] + red[6] + red[7]) * (1.0f / 768.0f);
    float rstd = rsqrtf(var + 1e-5f);

#pragma unroll
    for (int c = 0; c < 3; ++c) {
        int d = t + c * 256;
        Hb[(long)row * Dm + d] =
            __float2bfloat16((x[c] - mu) * rstd * gamma[d] + beta[d]);
    }
}

// ---------------------------------------------------------------------------
extern "C" void kernel_launch(void* const* d_in, const int* in_sizes, int n_in,
                              void* d_out, int out_size, void* d_ws, size_t ws_size,
                              hipStream_t stream)
{
    const int*   Ms    = (const int*)d_in[0];
    const float* Ev    = (const float*)d_in[1];
    const float* Ey    = (const float*)d_in[2];
    const float* WA    = (const float*)d_in[3];
    const float* WO    = (const float*)d_in[4];
    const float* gamma = (const float*)d_in[5];
    const float* beta  = (const float*)d_in[6];

    float* y_out = (float*)d_out;                       // [4096][30000]
    float* A_out = y_out + (size_t)Tok * Yv;            // [8][512][512]

    char* ws = (char*)d_ws;
    size_t off = 0;
    auto alloc = [&](size_t n) { char* p = ws + off; off += (n + 255) & ~(size_t)255; return p; };
    bf16*  Xb    = (bf16*) alloc((size_t)Tok * Dm * 2);
    bf16*  WcatT = (bf16*) alloc((size_t)2 * Dm * Dm * 2);
    bf16*  QXWb  = (bf16*) alloc((size_t)Tok * 1536 * 2);
    bf16*  XWobT = (bf16*) alloc((size_t)Tok * Dm * 2);
    float* Lf    = (float*)alloc((size_t)Tok * Nseq * 4);
    bf16*  Ab    = (bf16*) alloc((size_t)Tok * Nseq * 2);
    float* Qc    = (float*)alloc((size_t)Tok * Dm * 4);
    bf16*  Hb    = (bf16*) alloc((size_t)Tok * Dm * 2);
    bf16*  Eyb   = (bf16*) alloc((size_t)Ypad * Dm * 2);

    // 1. convert + pad E_y
    k_cvt_ey<<<dim3(11328), dim3(256), 0, stream>>>(Ey, Eyb);
    // 2. transpose-convert W_A, W_O into packed [1536][768]
    k_wT<<<dim3(24, 24, 2), dim3(32, 8), 0, stream>>>(WA, WO, WcatT);
    // 3. gather embeddings
    k_gather<<<dim3(Tok), dim3(192), 0, stream>>>(Ms, Ev, Xb);
    // 4. [QW | XWo] = X @ [W_A^T; W_O^T]  (bf16 out, N=1536)
    gemm_bt<true><<<dim3(384), dim3(256), 0, stream>>>(
        Xb, WcatT, (void*)QXWb, Tok, 1536, Dm, Dm, 1536, 0L, 0L, 0L);
    // 5. logits = QW @ X^T per batch (f32 out)
    gemm_bt<false><<<dim3(16, 1, 8), dim3(256), 0, stream>>>(
        QXWb, Xb, (void*)Lf, Nseq, Nseq, Dm, 1536, Nseq,
        (long)Nseq * 1536, (long)Nseq * Dm, (long)Nseq * Nseq);
    // 6. bias + mask + softmax -> A (f32 in d_out, nt) and Ab (bf16)
    k_softmax<<<dim3(Tok), dim3(256), 0, stream>>>(Lf, Ms, A_out, Ab);
    // 7. transpose XWo slice per batch
    k_xwoT<<<dim3(16, 24, 8), dim3(32, 8), 0, stream>>>(QXWb, XWobT);
    // 8. Qc = A @ XWo per batch (f32 out)
    gemm_bt<false><<<dim3(24, 1, 8), dim3(256), 0, stream>>>(
        Ab, XWobT, (void*)Qc, Nseq, Dm, Nseq, Nseq, Dm,
        (long)Nseq * Nseq, (long)Dm * Nseq, (long)Nseq * Dm);
    // 9. H = LN(Qc + X)
    k_ln<<<dim3(Tok), dim3(256), 0, stream>>>(Qc, Ms, Ev, gamma, beta, Hb);
    // 10. y_logits = H @ E_y^T  (128x256 BK=32 4-phase, 2 blocks/CU)
    gemm_big<<<dim3(32 * (Ypad / 256)), dim3(512), 0, stream>>>(Hb, Eyb, y_out);
}

// Round 8
// 350.150 us; speedup vs baseline: 1.2767x; 1.0330x over previous
//
#include <hip/hip_runtime.h>
#include <hip/hip_bf16.h>

using bf16 = __hip_bfloat16;
typedef __attribute__((ext_vector_type(8))) short bf16x8;
typedef __attribute__((ext_vector_type(4))) float f32x4;

#define DEV __device__ __forceinline__

#define AS1 __attribute__((address_space(1)))
#define AS3 __attribute__((address_space(3)))
#define SB  __builtin_amdgcn_sched_barrier(0)
#define BARR __builtin_amdgcn_s_barrier()
#define LG0 asm volatile("s_waitcnt lgkmcnt(0)" ::: "memory")
#define VM3 asm volatile("s_waitcnt vmcnt(3)" ::: "memory")
#define VM1 asm volatile("s_waitcnt vmcnt(1)" ::: "memory")
#define VM0 asm volatile("s_waitcnt vmcnt(0)" ::: "memory")

// ---------------------------------------------------------------------------
// constants
static constexpr int Bsz = 8, Nseq = 512, Dm = 768, Vv = 30000, Yv = 30000;
static constexpr int Ypad = 30208;               // 118 tiles of 256
static constexpr int Tok = Bsz * Nseq;           // 4096
static constexpr int NT = Dm / 32;               // 24 K-tiles of 32

// ---------------------------------------------------------------------------
// Big GEMM (round-7 verbatim): C[4096][Yv] f32 = A[4096][768] * B[Ypad][768]^T
// 128M x 256N tile, BK=32, 8 waves, 48 KiB LDS -> 2 blocks/CU, 4-phase/iter,
// vmcnt(3) counted waits, XOR-swizzled LDS, XCD swizzle, nt stores.
__global__ __launch_bounds__(512, 4)
void gemm_big(const bf16* __restrict__ Ag, const bf16* __restrict__ Bg,
              float* __restrict__ Cg)
{
    __shared__ bf16 sm[6][4096];                 // 6 x 8 KiB = 48 KiB

    int bid = blockIdx.x;
    { int cpx = gridDim.x >> 3; bid = (bid & 7) * cpx + (bid >> 3); }
    const int mT = bid & 31;
    const int nT = bid >> 5;

    const int tid  = threadIdx.x;
    const int lane = tid & 63;
    const int wid  = tid >> 6;
    const int wm   = wid >> 2;
    const int wn   = wid & 3;

    const int lr = tid >> 2;
    const int sc = ((tid & 3) ^ (lr & 3)) << 3;
    const bf16* aS  = Ag + (long)(mT * 128 + lr) * Dm + sc;
    const bf16* bS0 = Bg + (long)(nT * 256 + lr) * Dm + sc;
    const bf16* bS1 = bS0 + (long)128 * Dm;
    const int ldsW = wid << 9;

    const int fl = lane & 15;
    const int fh = lane >> 4;
    const int e0 = (fh ^ (fl & 3)) << 3;
    const int aro = (wm * 64 + fl) * 32;
    const int bro = (wn * 32 + fl) * 32;

    bf16x8 afr[4], bfr[2];
    f32x4 acc[4][2][2] = {};

#define STG(CI, PTR, T)                                                        \
    __builtin_amdgcn_global_load_lds((const AS1 void*)((PTR) + (T) * 32),      \
        (AS3 void*)&sm[CI][ldsW], 16, 0, 0);
#define RA(CI)                                                                 \
    _Pragma("unroll") for (int mm = 0; mm < 4; ++mm)                           \
        afr[mm] = *(const bf16x8*)&sm[CI][aro + mm * 512 + e0];
#define RB(CI)                                                                 \
    _Pragma("unroll") for (int nn = 0; nn < 2; ++nn)                           \
        bfr[nn] = *(const bf16x8*)&sm[CI][bro + nn * 512 + e0];
#define MF8(NQ)                                                                \
    __builtin_amdgcn_s_setprio(1);                                             \
    _Pragma("unroll") for (int mm = 0; mm < 4; ++mm)                           \
    _Pragma("unroll") for (int nn = 0; nn < 2; ++nn)                           \
        acc[mm][NQ][nn] = __builtin_amdgcn_mfma_f32_16x16x32_bf16(             \
            afr[mm], bfr[nn], acc[mm][NQ][nn], 0, 0, 0);                       \
    __builtin_amdgcn_s_setprio(0);

    STG(0, aS, 0) STG(1, bS0, 0) STG(2, bS1, 0) STG(3, aS, 1) STG(4, bS0, 1)
    VM3; SB; BARR; SB;

#pragma unroll 1
    for (int t = 0; t < NT - 2; t += 2) {
        RA(0) RB(1)
        STG(5, bS1, t + 1)
        VM3; SB; BARR; LG0; SB;
        MF8(0)
        SB; BARR; SB;
        RB(2)
        STG(0, aS, t + 2) STG(1, bS0, t + 2)
        VM3; SB; BARR; LG0; SB;
        MF8(1)
        SB; BARR; SB;
        RA(3) RB(4)
        STG(2, bS1, t + 2)
        VM3; SB; BARR; LG0; SB;
        MF8(0)
        SB; BARR; SB;
        RB(5)
        STG(3, aS, t + 3) STG(4, bS0, t + 3)
        VM3; SB; BARR; LG0; SB;
        MF8(1)
        SB; BARR; SB;
    }

    {
        RA(0) RB(1)
        STG(5, bS1, NT - 1)
        VM3; SB; BARR; LG0; SB;
        MF8(0)
        SB; BARR; SB;
        RB(2)
        VM1; SB; BARR; LG0; SB;
        MF8(1)
        SB; BARR; SB;
        RA(3) RB(4)
        VM0; SB; BARR; LG0; SB;
        MF8(0)
        SB; BARR; SB;
        RB(5)
        SB; BARR; LG0; SB;
        MF8(1)
    }

    const int rB = mT * 128 + wm * 64 + fh * 4;
    const int cB = nT * 256 + wn * 32 + fl;
#pragma unroll
    for (int mm = 0; mm < 4; ++mm)
#pragma unroll
    for (int nq = 0; nq < 2; ++nq)
#pragma unroll
    for (int nn = 0; nn < 2; ++nn) {
        const int c = cB + nq * 128 + nn * 16;
        if (c >= Yv) continue;
        const int r = rB + mm * 16;
#pragma unroll
        for (int j = 0; j < 4; ++j)
            __builtin_nontemporal_store(acc[mm][nq][nn][j],
                                        Cg + (long)(r + j) * Yv + c);
    }
#undef STG
#undef RA
#undef RB
#undef MF8
}

// ---------------------------------------------------------------------------
// GEMM: C[M][Nc] = A[M][K](lda) * B[Nc][K]^T   (m97-structure, small GEMMs)
template<bool STORE_BF16>
__global__ __launch_bounds__(256)
void gemm_bt(const bf16* __restrict__ Ag, const bf16* __restrict__ Bg,
             void* __restrict__ Cg, int M, int Nc, int K, int lda, int ldc,
             long sA, long sB, long sC)
{
    __shared__ bf16 As[128 * 32];
    __shared__ bf16 Bs[128 * 32];

    const int bz = blockIdx.z;
    const bf16* A  = Ag + (long)bz * sA;
    const bf16* Bm = Bg + (long)bz * sB;

    const int bid = blockIdx.x;
    const int nTilesM = M >> 7;
    const int mTile = bid % nTilesM;
    const int nTile = bid / nTilesM;

    const int tid  = threadIdx.x;
    const int wave = tid >> 6;
    const int lane = tid & 63;

    const int sRow = (wave << 4) + (lane >> 2);
    const int sCol = (lane & 3) << 3;

    const long aBase = (long)(mTile * 128) * lda;
    const long bBase = (long)(nTile * 128) * K;

    const int fl = lane & 15;
    const int fh = lane >> 4;
    const int wRow = (wave >> 1) << 6;
    const int wCol = (wave & 1) << 6;

    f32x4 acc[4][4] = {};

    for (int k0 = 0; k0 < K; k0 += 32) {
#pragma unroll
        for (int t = 0; t < 2; ++t) {
            const bf16* gA = A  + aBase + (long)(t * 64 + sRow) * lda + (k0 + sCol);
            const bf16* gB = Bm + bBase + (long)(t * 64 + sRow) * K + (k0 + sCol);
            bf16* lA = &As[(t * 64 + (wave << 4)) * 32];
            bf16* lB = &Bs[(t * 64 + (wave << 4)) * 32];
            __builtin_amdgcn_global_load_lds(
                (const AS1 void*)gA, (AS3 void*)lA, 16, 0, 0);
            __builtin_amdgcn_global_load_lds(
                (const AS1 void*)gB, (AS3 void*)lB, 16, 0, 0);
        }
        __syncthreads();

        bf16x8 af[4], bfg[4];
#pragma unroll
        for (int m = 0; m < 4; ++m)
            af[m] = *(const bf16x8*)&As[(wRow + m * 16 + fl) * 32 + fh * 8];
#pragma unroll
        for (int n = 0; n < 4; ++n)
            bfg[n] = *(const bf16x8*)&Bs[(wCol + n * 16 + fl) * 32 + fh * 8];
#pragma unroll
        for (int m = 0; m < 4; ++m)
#pragma unroll
            for (int n = 0; n < 4; ++n)
                acc[m][n] = __builtin_amdgcn_mfma_f32_16x16x32_bf16(
                    af[m], bfg[n], acc[m][n], 0, 0, 0);
        __syncthreads();
    }

    const int rBase = mTile * 128 + wRow + fh * 4;
    const int cBase = nTile * 128 + wCol + fl;
#pragma unroll
    for (int m = 0; m < 4; ++m) {
#pragma unroll
        for (int n = 0; n < 4; ++n) {
            int gc = cBase + n * 16;
            int gr = rBase + m * 16;
            if (STORE_BF16) {
                bf16* C = (bf16*)Cg + (long)bz * sC;
#pragma unroll
                for (int j = 0; j < 4; ++j)
                    C[(long)(gr + j) * ldc + gc] = __float2bfloat16(acc[m][n][j]);
            } else {
                float* C = (float*)Cg + (long)bz * sC;
#pragma unroll
                for (int j = 0; j < 4; ++j)
                    C[(long)(gr + j) * ldc + gc] = acc[m][n][j];
            }
        }
    }
}

// ---------------------------------------------------------------------------
// 64x128-tile GEMM (bf16 out): C[M][Nc] = A[M][K](lda) * B[Nc][K]^T
// 4 waves, each computes 64x32 (wRow=0, wCol=wave*32). For the logits GEMM.
__global__ __launch_bounds__(256)
void gemm_bt64(const bf16* __restrict__ Ag, const bf16* __restrict__ Bg,
               bf16* __restrict__ Cg, int M, int K, int lda, int ldc,
               long sA, long sB, long sC)
{
    __shared__ bf16 As[64 * 32];
    __shared__ bf16 Bs[128 * 32];

    const int bz = blockIdx.z;
    const bf16* A  = Ag + (long)bz * sA;
    const bf16* Bm = Bg + (long)bz * sB;
    bf16* C = Cg + (long)bz * sC;

    const int bid = blockIdx.x;
    const int nTilesM = M >> 6;
    const int mTile = bid % nTilesM;
    const int nTile = bid / nTilesM;

    const int tid  = threadIdx.x;
    const int wave = tid >> 6;
    const int lane = tid & 63;

    const int sRow = tid >> 2;                   // 0..63
    const int sCol = (tid & 3) << 3;

    const long aBase = (long)(mTile * 64) * lda;
    const long bBase = (long)(nTile * 128) * K;

    const int fl = lane & 15;
    const int fh = lane >> 4;

    f32x4 acc[4][2] = {};

    for (int k0 = 0; k0 < K; k0 += 32) {
        // A: 64x32 = 256 chunks, 1/thread
        __builtin_amdgcn_global_load_lds(
            (const AS1 void*)(A + aBase + (long)sRow * lda + (k0 + sCol)),
            (AS3 void*)&As[wave * 512], 16, 0, 0);
        // B: 128x32 = 512 chunks, 2/thread
#pragma unroll
        for (int t = 0; t < 2; ++t)
            __builtin_amdgcn_global_load_lds(
                (const AS1 void*)(Bm + bBase + (long)(t * 64 + sRow) * K + (k0 + sCol)),
                (AS3 void*)&Bs[t * 2048 + wave * 512], 16, 0, 0);
        __syncthreads();

        bf16x8 af[4], bfg[2];
#pragma unroll
        for (int m = 0; m < 4; ++m)
            af[m] = *(const bf16x8*)&As[(m * 16 + fl) * 32 + fh * 8];
#pragma unroll
        for (int n = 0; n < 2; ++n)
            bfg[n] = *(const bf16x8*)&Bs[(wave * 32 + n * 16 + fl) * 32 + fh * 8];
#pragma unroll
        for (int m = 0; m < 4; ++m)
#pragma unroll
            for (int n = 0; n < 2; ++n)
                acc[m][n] = __builtin_amdgcn_mfma_f32_16x16x32_bf16(
                    af[m], bfg[n], acc[m][n], 0, 0, 0);
        __syncthreads();
    }

    const int rBase = mTile * 64 + fh * 4;
    const int cBase = nTile * 128 + wave * 32 + fl;
#pragma unroll
    for (int m = 0; m < 4; ++m)
#pragma unroll
    for (int n = 0; n < 2; ++n) {
        const int gc = cBase + n * 16;
        const int gr = rBase + m * 16;
#pragma unroll
        for (int j = 0; j < 4; ++j)
            C[(long)(gr + j) * ldc + gc] = __float2bfloat16(acc[m][n][j]);
    }
}

// ---------------------------------------------------------------------------
// Fused prep: [0,11328) cvt_ey | [11328,12480) wT | [12480,16576) gather
static constexpr int PREP_CVT = 11328, PREP_WT = 1152, PREP_GATHER = 4096;

__global__ __launch_bounds__(256)
void k_prep(const float* __restrict__ Ey, bf16* __restrict__ Eyb,
            const float* __restrict__ WA, const float* __restrict__ WO,
            bf16* __restrict__ Wcat,
            const int* __restrict__ Ms, const float* __restrict__ Ev,
            bf16* __restrict__ Xb)
{
    __shared__ float t[32][33];
    const int b = blockIdx.x;
    const int tid = threadIdx.x;

    if (b < PREP_CVT) {
        // E_y f32 [30000][768] -> bf16 [30208][768], pad rows zero
        const long idx = ((long)b * 256 + tid) * 8;
        const int row = (int)(idx / Dm);
        union { bf16 h[8]; uint4 u; } pk;
        if (row < Yv) {
            const f32x4* s = (const f32x4*)(Ey + idx);
            f32x4 a = __builtin_nontemporal_load(s);
            f32x4 c = __builtin_nontemporal_load(s + 1);
#pragma unroll
            for (int i = 0; i < 4; ++i) {
                pk.h[i]     = __float2bfloat16(a[i]);
                pk.h[4 + i] = __float2bfloat16(c[i]);
            }
        } else {
#pragma unroll
            for (int i = 0; i < 8; ++i) pk.h[i] = __float2bfloat16(0.f);
        }
        *(uint4*)(Eyb + idx) = pk.u;
    } else if (b < PREP_CVT + PREP_WT) {
        // W f32 [768][768] -> Wcat^T bf16 [1536][768]
        const int rem = b - PREP_CVT;
        const int z = rem / 576, r2 = rem % 576;
        const int bx = (r2 % 24) * 32, by = (r2 / 24) * 32;
        const float* W = z ? WO : WA;
        bf16* WT = Wcat + (size_t)z * Dm * Dm;
        const int tx = tid & 31, ty = tid >> 5;
#pragma unroll
        for (int i = 0; i < 32; i += 8)
            t[ty + i][tx] = W[(long)(bx + ty + i) * Dm + (by + tx)];
        __syncthreads();
#pragma unroll
        for (int i = 0; i < 32; i += 8)
            WT[(long)(by + ty + i) * Dm + (bx + tx)] = __float2bfloat16(t[tx][ty + i]);
    } else {
        // X = E_v[M_s] -> bf16 [4096][768]
        const int token = b - (PREP_CVT + PREP_WT);
        if (tid < 192) {
            const int id = Ms[token];
            const int d = tid * 4;
            float4 v = *(const float4*)(Ev + (long)id * Dm + d);
            union { bf16 h[4]; uint2 u; } pk;
            pk.h[0] = __float2bfloat16(v.x); pk.h[1] = __float2bfloat16(v.y);
            pk.h[2] = __float2bfloat16(v.z); pk.h[3] = __float2bfloat16(v.w);
            *(uint2*)(Xb + (long)token * Dm + d) = pk.u;
        }
    }
}

// XWo slice of QXW bf16 [B][512][1536](+768) -> [B][768][512]
__global__ void k_xwoT(const bf16* __restrict__ Xo, bf16* __restrict__ XoT)
{
    __shared__ bf16 t[32][33];
    int b = blockIdx.z;
    const bf16* src = Xo + (long)b * Nseq * 1536 + 768;
    bf16* dst = XoT + (long)b * Dm * Nseq;
    int bx = blockIdx.x * 32;
    int by = blockIdx.y * 32;
    int tx = threadIdx.x, ty = threadIdx.y;
#pragma unroll
    for (int i = 0; i < 32; i += 8)
        t[ty + i][tx] = src[(long)(bx + ty + i) * 1536 + (by + tx)];
    __syncthreads();
#pragma unroll
    for (int i = 0; i < 32; i += 8)
        dst[(long)(by + ty + i) * Nseq + (bx + tx)] = t[tx][ty + i];
}

// ---------------------------------------------------------------------------
DEV float waveMax(float v) {
#pragma unroll
    for (int o = 32; o > 0; o >>= 1) v = fmaxf(v, __shfl_xor(v, o, 64));
    return v;
}
DEV float waveSum(float v) {
#pragma unroll
    for (int o = 32; o > 0; o >>= 1) v += __shfl_xor(v, o, 64);
    return v;
}

// softmax over j of (L[b,i,j] + (j-i)) with mask; L is bf16, bias in f32
__global__ __launch_bounds__(256) void k_softmax(const bf16* __restrict__ L,
                                                 const int* __restrict__ Ms,
                                                 float* __restrict__ Aout,
                                                 bf16* __restrict__ Ab)
{
    __shared__ float red[8];
    int row = blockIdx.x;
    int b = row >> 9, i = row & 511;
    const bf16* l = L + (long)row * Nseq;
    const int* ms = Ms + (b << 9);
    int t = threadIdx.x;
    int wid = t >> 6, lane = t & 63;
    int j0 = t, j1 = t + 256;

    float a0 = __bfloat162float(l[j0]) + (float)(j0 - i);
    float a1 = __bfloat162float(l[j1]) + (float)(j1 - i);
    if (ms[j0] == 0) a0 = -1e12f;
    if (ms[j1] == 0) a1 = -1e12f;

    float m = waveMax(fmaxf(a0, a1));
    if (lane == 0) red[wid] = m;
    __syncthreads();
    m = fmaxf(fmaxf(red[0], red[1]), fmaxf(red[2], red[3]));

    float e0 = expf(a0 - m), e1 = expf(a1 - m);
    float s = waveSum(e0 + e1);
    if (lane == 0) red[4 + wid] = s;
    __syncthreads();
    s = red[4] + red[5] + red[6] + red[7];
    float inv = 1.0f / s;

    float r0 = e0 * inv, r1 = e1 * inv;
    __builtin_nontemporal_store(r0, &Aout[(long)row * Nseq + j0]);
    __builtin_nontemporal_store(r1, &Aout[(long)row * Nseq + j1]);
    Ab[(long)row * Nseq + j0] = __float2bfloat16(r0);
    Ab[(long)row * Nseq + j1] = __float2bfloat16(r1);
}

// H = LN(Qc + X) * gamma + beta  -> bf16  (X read as bf16)
__global__ __launch_bounds__(256) void k_ln(const float* __restrict__ Qc,
                                            const bf16* __restrict__ Xb,
                                            const float* __restrict__ gamma,
                                            const float* __restrict__ beta,
                                            bf16* __restrict__ Hb)
{
    __shared__ float red[8];
    int row = blockIdx.x;
    const float* q = Qc + (long)row * Dm;
    const bf16* e = Xb + (long)row * Dm;
    int t = threadIdx.x;
    int wid = t >> 6, lane = t & 63;

    float x[3];
#pragma unroll
    for (int c = 0; c < 3; ++c)
        x[c] = q[t + c * 256] + __bfloat162float(e[t + c * 256]);

    float s = waveSum(x[0] + x[1] + x[2]);
    if (lane == 0) red[wid] = s;
    __syncthreads();
    float mu = (red[0] + red[1] + red[2] + red[3]) * (1.0f / 768.0f);

    float vs = 0.f;
#pragma unroll
    for (int c = 0; c < 3; ++c) { float d = x[c] - mu; vs += d * d; }
    vs = waveSum(vs);
    if (lane == 0) red[4 + wid] = vs;
    __syncthreads();
    float var = (red[4] + red[5] + red[6] + red[7]) * (1.0f / 768.0f);
    float rstd = rsqrtf(var + 1e-5f);

#pragma unroll
    for (int c = 0; c < 3; ++c) {
        int d = t + c * 256;
        Hb[(long)row * Dm + d] =
            __float2bfloat16((x[c] - mu) * rstd * gamma[d] + beta[d]);
    }
}

// ---------------------------------------------------------------------------
extern "C" void kernel_launch(void* const* d_in, const int* in_sizes, int n_in,
                              void* d_out, int out_size, void* d_ws, size_t ws_size,
                              hipStream_t stream)
{
    const int*   Ms    = (const int*)d_in[0];
    const float* Ev    = (const float*)d_in[1];
    const float* Ey    = (const float*)d_in[2];
    const float* WA    = (const float*)d_in[3];
    const float* WO    = (const float*)d_in[4];
    const float* gamma = (const float*)d_in[5];
    const float* beta  = (const float*)d_in[6];

    float* y_out = (float*)d_out;                       // [4096][30000]
    float* A_out = y_out + (size_t)Tok * Yv;            // [8][512][512]

    char* ws = (char*)d_ws;
    size_t off = 0;
    auto alloc = [&](size_t n) { char* p = ws + off; off += (n + 255) & ~(size_t)255; return p; };
    bf16*  Xb    = (bf16*) alloc((size_t)Tok * Dm * 2);
    bf16*  WcatT = (bf16*) alloc((size_t)2 * Dm * Dm * 2);
    bf16*  QXWb  = (bf16*) alloc((size_t)Tok * 1536 * 2);
    bf16*  XWobT = (bf16*) alloc((size_t)Tok * Dm * 2);
    bf16*  Lb    = (bf16*) alloc((size_t)Tok * Nseq * 2);
    bf16*  Ab    = (bf16*) alloc((size_t)Tok * Nseq * 2);
    float* Qc    = (float*)alloc((size_t)Tok * Dm * 4);
    bf16*  Hb    = (bf16*) alloc((size_t)Tok * Dm * 2);
    bf16*  Eyb   = (bf16*) alloc((size_t)Ypad * Dm * 2);

    // 1. fused prep: E_y convert+pad | W transpose | embedding gather
    k_prep<<<dim3(PREP_CVT + PREP_WT + PREP_GATHER), dim3(256), 0, stream>>>(
        Ey, Eyb, WA, WO, WcatT, Ms, Ev, Xb);
    // 2. [QW | XWo] = X @ [W_A^T; W_O^T]  (bf16 out, N=1536)
    gemm_bt<true><<<dim3(384), dim3(256), 0, stream>>>(
        Xb, WcatT, (void*)QXWb, Tok, 1536, Dm, Dm, 1536, 0L, 0L, 0L);
    // 3. logits = QW @ X^T per batch (bf16 out, 64x128 tiles, 256 blocks)
    gemm_bt64<<<dim3(32, 1, 8), dim3(256), 0, stream>>>(
        QXWb, Xb, Lb, Nseq, Dm, 1536, Nseq,
        (long)Nseq * 1536, (long)Nseq * Dm, (long)Nseq * Nseq);
    // 4. bias + mask + softmax -> A (f32 in d_out, nt) and Ab (bf16)
    k_softmax<<<dim3(Tok), dim3(256), 0, stream>>>(Lb, Ms, A_out, Ab);
    // 5. transpose XWo slice per batch
    k_xwoT<<<dim3(16, 24, 8), dim3(32, 8), 0, stream>>>(QXWb, XWobT);
    // 6. Qc = A @ XWo per batch (f32 out)
    gemm_bt<false><<<dim3(24, 1, 8), dim3(256), 0, stream>>>(
        Ab, XWobT, (void*)Qc, Nseq, Dm, Nseq, Nseq, Dm,
        (long)Nseq * Nseq, (long)Dm * Nseq, (long)Nseq * Dm);
    // 7. H = LN(Qc + X)
    k_ln<<<dim3(Tok), dim3(256), 0, stream>>>(Qc, Xb, gamma, beta, Hb);
    // 8. y_logits = H @ E_y^T  (128x256 BK=32 4-phase, 2 blocks/CU)
    gemm_big<<<dim3(32 * (Ypad / 256)), dim3(512), 0, stream>>>(Hb, Eyb, y_out);
}